// Round 5
// baseline (100.316 us; speedup 1.0000x reference)
//
#include <hip/hip_runtime.h>

// QuerySpecificClusterModel: B=256 samples, n=64 points, d=768.
// Round 5: identical to round 4 EXCEPT the occupancy attributes.
// Root cause of rounds 2-4's ~100us: allocator targets 4 waves/EU -> 128
// VGPRs -> ~80B/thread scratch spill (WRITE_SIZE 41-52 MB). launch_bounds'
// 2nd arg is only a lower bound; amdgpu_waves_per_eu(2,2) pins the target
// occupancy to 2 waves/EU (= our LDS-capped reality) -> 256-VGPR budget ->
// no spill.

#define NPTS 64
#define DIM 768
#define CH 128
#define NCH 6
#define NT 512
#define BIGF 1e9f

// ---- DPP lexicographic argmin over 64 lanes: (val, flatidx), lowest idx tie ----
template <int CTRL>
__device__ __forceinline__ void amin_step(float& vf, int& fi) {
  int sv = __builtin_amdgcn_update_dpp(__float_as_int(vf), __float_as_int(vf),
                                       CTRL, 0xF, 0xF, false);
  int si = __builtin_amdgcn_update_dpp(fi, fi, CTRL, 0xF, 0xF, false);
  float svf = __int_as_float(sv);
  bool take = (svf < vf) || (svf == vf && si < fi);
  vf = take ? svf : vf;
  fi = take ? si : fi;
}

__device__ __forceinline__ void argmin64(float& vf, int& fi) {
  amin_step<0x121>(vf, fi);   // row_ror:1
  amin_step<0x122>(vf, fi);   // row_ror:2
  amin_step<0x124>(vf, fi);   // row_ror:4
  amin_step<0x128>(vf, fi);   // row_ror:8
  amin_step<0x142>(vf, fi);   // row_bcast:15
  amin_step<0x143>(vf, fi);   // row_bcast:31
  vf = __int_as_float(__builtin_amdgcn_readlane(__float_as_int(vf), 63));
  fi = __builtin_amdgcn_readlane(fi, 63);
}

// ---- tree-reduce partial helpers (XOR slot-swizzle: <=4-way conflicts) ----
__device__ __forceinline__ void wr_partial(float* __restrict__ Pb,
                                           const float (&acc)[8][8], int g, int h) {
  #pragma unroll
  for (int ii = 0; ii < 8; ++ii) {
    const int row = (g << 3) + ii;
    #pragma unroll
    for (int jq = 0; jq < 2; ++jq) {
      const int sl = ((h << 1) + jq) ^ g;
      float4 v = make_float4(acc[ii][jq * 4 + 0], acc[ii][jq * 4 + 1],
                             acc[ii][jq * 4 + 2], acc[ii][jq * 4 + 3]);
      *reinterpret_cast<float4*>(Pb + (row << 6) + (sl << 2)) = v;
    }
  }
}

__device__ __forceinline__ void rd_accum(const float* __restrict__ Pb,
                                         float (&acc)[8][8], int g, int h) {
  #pragma unroll
  for (int ii = 0; ii < 8; ++ii) {
    const int row = (g << 3) + ii;
    #pragma unroll
    for (int jq = 0; jq < 2; ++jq) {
      const int sl = ((h << 1) + jq) ^ g;
      float4 v = *reinterpret_cast<const float4*>(Pb + (row << 6) + (sl << 2));
      acc[ii][jq * 4 + 0] += v.x; acc[ii][jq * 4 + 1] += v.y;
      acc[ii][jq * 4 + 2] += v.z; acc[ii][jq * 4 + 3] += v.w;
    }
  }
}

__global__ __attribute__((amdgpu_flat_work_group_size(NT, NT)))
__attribute__((amdgpu_waves_per_eu(2, 2)))
void fused_kernel(
    const float* __restrict__ q,      // [256,768]
    const float* __restrict__ psg,    // [256,64,768]
    const int*   __restrict__ labels, // [256,64]
    float* __restrict__ simS_o, float* __restrict__ disS_o,
    int* __restrict__ simC_o, int* __restrict__ errC_o)
{
  __shared__ __align__(16) float s[NPTS][132];        // staged scaled chunk (swizzled)
  __shared__ __align__(16) float P[4][NPTS][NPTS];    // tree-reduce scratch (64KB)
  __shared__ __align__(16) float Dw[NPTS][65];        // distance matrix
  __shared__ float diag[NPTS];
  __shared__ __align__(16) int cls[NPTS];

  const int b = blockIdx.x;
  const int t = threadIdx.x;
  const int w = t >> 6;          // wave id 0..7
  const int lane = t & 63;
  const int g = lane >> 3;
  const int h = lane & 7;
  const int i0 = g << 3;
  const int j0 = h << 3;

  const float* qb = q + (size_t)b * DIM;
  const float* pb = psg + (size_t)b * NPTS * DIM;

  float acc[8][8] = {};

  const int kvq = t & 31;        // float4 col within chunk (staging)
  const int irb = t >> 5;        // staging row base 0..15

  for (int c = 0; c < NCH; ++c) {
    // stage scaled chunk c (short-lived regs only)
    float4 qv = *reinterpret_cast<const float4*>(qb + c * CH + (kvq << 2));
    #pragma unroll
    for (int r = 0; r < 4; ++r) {
      const int i = irb + (r << 4);
      float4 pv = *reinterpret_cast<const float4*>(
          pb + (size_t)i * DIM + c * CH + (kvq << 2));
      float4 sv = make_float4(pv.x * qv.x, pv.y * qv.y, pv.z * qv.z, pv.w * qv.w);
      *reinterpret_cast<float4*>(&s[i][(kvq ^ (i >> 3)) << 2]) = sv;
    }
    __syncthreads();
    // K split across 8 waves: wave w owns k4 = w*4 .. w*4+3
    #pragma unroll
    for (int kk = 0; kk < 4; ++kk) {
      const int k4 = (w << 2) + kk;
      float4 a4[8];
      #pragma unroll
      for (int ii = 0; ii < 8; ++ii) {
        const int row = i0 + ii;
        a4[ii] = *reinterpret_cast<const float4*>(&s[row][(k4 ^ (row >> 3)) << 2]);
      }
      #pragma unroll
      for (int jj = 0; jj < 8; ++jj) {
        const int row = j0 + jj;
        float4 b4 = *reinterpret_cast<const float4*>(&s[row][(k4 ^ (row >> 3)) << 2]);
        #pragma unroll
        for (int ii = 0; ii < 8; ++ii) {
          acc[ii][jj] += a4[ii].x * b4.x;
          acc[ii][jj] += a4[ii].y * b4.y;
          acc[ii][jj] += a4[ii].z * b4.z;
          acc[ii][jj] += a4[ii].w * b4.w;
        }
      }
    }
    __syncthreads();
  }

  // ---- tree reduce of 8 wave-partials into wave 0 (3 steps, 6 barriers) ----
  if (w >= 4) wr_partial(&P[w - 4][0][0], acc, g, h);
  __syncthreads();
  if (w < 4) rd_accum(&P[w][0][0], acc, g, h);
  __syncthreads();
  if (w == 2) wr_partial(&P[0][0][0], acc, g, h);
  if (w == 3) wr_partial(&P[1][0][0], acc, g, h);
  __syncthreads();
  if (w < 2) rd_accum(&P[w][0][0], acc, g, h);
  __syncthreads();
  if (w == 1) wr_partial(&P[0][0][0], acc, g, h);
  __syncthreads();
  if (w != 0) return;            // wave 0 continues alone; same-wave LDS in-order
  rd_accum(&P[0][0][0], acc, g, h);

  // diag (squared norms) then distances (diag exactly 0)
  if (g == h) {
    #pragma unroll
    for (int ii = 0; ii < 8; ++ii) diag[i0 + ii] = acc[ii][ii];
  }
  #pragma unroll
  for (int ii = 0; ii < 8; ++ii) {
    float di = diag[i0 + ii];
    #pragma unroll
    for (int jj = 0; jj < 8; ++jj) {
      float d2 = di + diag[j0 + jj] - 2.f * acc[ii][jj];
      d2 = fmaxf(d2, 0.f);
      Dw[i0 + ii][j0 + jj] = (d2 > 0.f) ? sqrtf(d2) : 0.f;
    }
  }

  // ---------------- clustering (single wave, lane l owns row l) -------------
  const int l = lane;
  float* Dm = &Dw[0][0];
  int tl = labels[b * NPTS + l];

  // label-equality mask + unique-label count via 8 ballots
  unsigned long long sMask = 0ull;
  int kcnt = 0;
  #pragma unroll
  for (int v = 0; v < 8; ++v) {
    unsigned long long mv = __ballot(tl == v);
    kcnt += (mv != 0ull) ? 1 : 0;
    if (tl == v) sMask = mv;
  }
  int simC = __popcll(sMask);

  // own-row scan: sim/dis sums + row min (strict <: lowest j wins ties)
  float simS = 0.f, disS = 0.f;
  float mval = BIGF; int midx = 0;
  const float* rowp = Dm + l * 65;
  #pragma unroll
  for (int j = 0; j < NPTS; ++j) {
    float v = rowp[j];
    bool sim = (sMask >> j) & 1ull;
    simS += sim ? v : 0.f;
    disS += sim ? 0.f : v;
    bool better = (j != l) && (v < mval);
    mval = better ? v : mval;
    midx = better ? j : midx;
  }
  Dm[l * 65 + l] = BIGF;         // reference inits diagonal to BIG

  unsigned long long actm = ~0ull;
  int cl = l;
  const int merges = NPTS - kcnt;
  #pragma unroll 1
  for (int m = 0; m < merges; ++m) {
    // global argmin over rows' (minval, flat=l*64+midx), lowest-flat tie-break
    bool act = (actm >> l) & 1ull;
    float vf = act ? mval : BIGF;
    int fi = (l << 6) | midx;
    argmin64(vf, fi);            // uniform result in all lanes
    const int a = fi >> 6;       // a < bb by symmetry + lowest-flat
    const int bb = fi & 63;

    // newrow[l] = min(D[l][a], D[l][bb]); update col a and row a
    float va = Dm[l * 65 + a];
    float vb = Dm[l * 65 + bb];
    float nr = fminf(va, vb);
    Dm[l * 65 + a] = nr;
    Dm[a * 65 + l] = nr;

    actm &= ~(1ull << bb);
    cl = (cl == bb) ? a : cl;

    // per-row min maintenance (nr >= mval always; col bb removed, col a -> nr)
    bool actrow = ((actm >> l) & 1ull) && (l != a);
    if (actrow) {
      if (midx == bb) midx = a;
      else if (nr == mval && a < midx) midx = a;
    }
    // fresh rescan for row a: candidates are nr across active lanes != a
    float cv = actrow ? nr : BIGF;
    int cj = l;
    argmin64(cv, cj);
    if (l == a) { mval = cv; midx = cj; }
  }

  // err count via masks: ec = popcount(clusterMask XOR labelMask)
  cls[l] = cl;
  unsigned long long cMask = 0ull;
  const int4* cp = reinterpret_cast<const int4*>(cls);
  #pragma unroll
  for (int jq = 0; jq < 16; ++jq) {
    int4 c4 = cp[jq];
    cMask |= ((unsigned long long)(c4.x == cl)) << (jq * 4 + 0);
    cMask |= ((unsigned long long)(c4.y == cl)) << (jq * 4 + 1);
    cMask |= ((unsigned long long)(c4.z == cl)) << (jq * 4 + 2);
    cMask |= ((unsigned long long)(c4.w == cl)) << (jq * 4 + 3);
  }
  int ec = __popcll(cMask ^ sMask);

  // wave reductions (deterministic butterfly; one-time)
  #pragma unroll
  for (int off = 32; off; off >>= 1) {
    simS += __shfl_xor(simS, off);
    disS += __shfl_xor(disS, off);
    simC += __shfl_xor(simC, off);
    ec   += __shfl_xor(ec, off);
  }
  if (l == 0) {
    simS_o[b] = simS; disS_o[b] = disS;
    simC_o[b] = simC; errC_o[b] = ec;
  }
}

__global__ __launch_bounds__(64) void finalize_kernel(
    const float* __restrict__ simS, const float* __restrict__ disS,
    const int* __restrict__ simC, const int* __restrict__ errC,
    float* __restrict__ out)
{
  const int l = threadIdx.x;
  double ss = 0.0, dd = 0.0, sc = 0.0, ec = 0.0;
  #pragma unroll
  for (int r = 0; r < 4; ++r) {
    int i = (r << 6) + l;        // fixed order -> deterministic
    ss += (double)simS[i];
    dd += (double)disS[i];
    sc += (double)simC[i];
    ec += (double)errC[i];
  }
  #pragma unroll
  for (int off = 32; off; off >>= 1) {
    ss += __shfl_xor(ss, off);
    dd += __shfl_xor(dd, off);
    sc += __shfl_xor(sc, off);
    ec += __shfl_xor(ec, off);
  }
  if (l == 0) {
    const double total = 256.0 * 4096.0;
    double ms = ss / sc;
    double md = dd / (total - sc);
    out[0] = (float)(ec / 256.0 + 0.5 * (ms - md));
  }
}

extern "C" void kernel_launch(void* const* d_in, const int* in_sizes, int n_in,
                              void* d_out, int out_size, void* d_ws, size_t ws_size,
                              hipStream_t stream) {
  const float* q      = (const float*)d_in[0];
  const float* psg    = (const float*)d_in[1];
  const int*   labels = (const int*)d_in[2];
  float* out = (float*)d_out;

  float* simS = (float*)d_ws;          // [256]
  float* disS = simS + 256;            // [256]
  int*   simC = (int*)(disS + 256);    // [256]
  int*   errC = simC + 256;            // [256]

  fused_kernel<<<256, NT, 0, stream>>>(q, psg, labels, simS, disS, simC, errC);
  finalize_kernel<<<1, 64, 0, stream>>>(simS, disS, simC, errC, out);
}

// Round 6
// 76.616 us; speedup vs baseline: 1.3093x; 1.3093x over previous
//
#include <hip/hip_runtime.h>

// QuerySpecificClusterModel: B=256 samples, n=64 points, d=768.
// Round 6: SPLIT into gram_kernel (512 thr/block, Gram+distances -> d_ws) and
// cluster_kernel (64 thr/block, merge loop + loss terms). Rationale:
// (a) rocprof now times each phase directly (occupancy-average inference said
//     tail ~65us, 5x my model — need ground truth);
// (b) the fused kernel's 128-VGPR spill (WRITE 41-52MB) likely comes from the
//     tail's fully-unrolled 64-iter scans; Gram-only should fit 128 VGPRs;
// (c) tail micro-opt: value-only DPP min + ballot/ffs argmin (lowest-lane ==
//     lowest-flat tie-break), bounded unrolls in scans.

#define NPTS 64
#define DIM 768
#define CH 128
#define NCH 6
#define NT 512
#define BIGF 1e9f

// ---- value-only DPP min reduce over 64 lanes, result broadcast ----
template <int CTRL>
__device__ __forceinline__ float vmin_step(float v) {
  int s = __builtin_amdgcn_update_dpp(__float_as_int(v), __float_as_int(v),
                                      CTRL, 0xF, 0xF, false);
  return fminf(v, __int_as_float(s));
}

__device__ __forceinline__ float minred64(float v) {
  v = vmin_step<0x121>(v);   // row_ror:1
  v = vmin_step<0x122>(v);   // row_ror:2
  v = vmin_step<0x124>(v);   // row_ror:4
  v = vmin_step<0x128>(v);   // row_ror:8
  v = vmin_step<0x142>(v);   // row_bcast:15
  v = vmin_step<0x143>(v);   // row_bcast:31
  return __int_as_float(__builtin_amdgcn_readlane(__float_as_int(v), 63));
}

// ---- tree-reduce partial helpers (XOR slot-swizzle: <=4-way conflicts) ----
__device__ __forceinline__ void wr_partial(float* __restrict__ Pb,
                                           const float (&acc)[8][8], int g, int h) {
  #pragma unroll
  for (int ii = 0; ii < 8; ++ii) {
    const int row = (g << 3) + ii;
    #pragma unroll
    for (int jq = 0; jq < 2; ++jq) {
      const int sl = ((h << 1) + jq) ^ g;
      float4 v = make_float4(acc[ii][jq * 4 + 0], acc[ii][jq * 4 + 1],
                             acc[ii][jq * 4 + 2], acc[ii][jq * 4 + 3]);
      *reinterpret_cast<float4*>(Pb + (row << 6) + (sl << 2)) = v;
    }
  }
}

__device__ __forceinline__ void rd_accum(const float* __restrict__ Pb,
                                         float (&acc)[8][8], int g, int h) {
  #pragma unroll
  for (int ii = 0; ii < 8; ++ii) {
    const int row = (g << 3) + ii;
    #pragma unroll
    for (int jq = 0; jq < 2; ++jq) {
      const int sl = ((h << 1) + jq) ^ g;
      float4 v = *reinterpret_cast<const float4*>(Pb + (row << 6) + (sl << 2));
      acc[ii][jq * 4 + 0] += v.x; acc[ii][jq * 4 + 1] += v.y;
      acc[ii][jq * 4 + 2] += v.z; acc[ii][jq * 4 + 3] += v.w;
    }
  }
}

// ================= kernel A: Gram + distance matrix -> d_ws =================
__global__ __launch_bounds__(NT) void gram_kernel(
    const float* __restrict__ q,      // [256,768]
    const float* __restrict__ psg,    // [256,64,768]
    float* __restrict__ Dg)           // [256,64,64]
{
  __shared__ __align__(16) float s[NPTS][132];        // staged scaled chunk
  __shared__ __align__(16) float P[4][NPTS][NPTS];    // tree-reduce scratch
  __shared__ float diag[NPTS];

  const int b = blockIdx.x;
  const int t = threadIdx.x;
  const int w = t >> 6;
  const int lane = t & 63;
  const int g = lane >> 3;
  const int h = lane & 7;
  const int i0 = g << 3;
  const int j0 = h << 3;

  const float* qb = q + (size_t)b * DIM;
  const float* pb = psg + (size_t)b * NPTS * DIM;

  float acc[8][8] = {};

  const int kvq = t & 31;
  const int irb = t >> 5;

  for (int c = 0; c < NCH; ++c) {
    float4 qv = *reinterpret_cast<const float4*>(qb + c * CH + (kvq << 2));
    #pragma unroll
    for (int r = 0; r < 4; ++r) {
      const int i = irb + (r << 4);
      float4 pv = *reinterpret_cast<const float4*>(
          pb + (size_t)i * DIM + c * CH + (kvq << 2));
      float4 sv = make_float4(pv.x * qv.x, pv.y * qv.y, pv.z * qv.z, pv.w * qv.w);
      *reinterpret_cast<float4*>(&s[i][(kvq ^ (i >> 3)) << 2]) = sv;
    }
    __syncthreads();
    #pragma unroll
    for (int kk = 0; kk < 4; ++kk) {
      const int k4 = (w << 2) + kk;
      float4 a4[8];
      #pragma unroll
      for (int ii = 0; ii < 8; ++ii) {
        const int row = i0 + ii;
        a4[ii] = *reinterpret_cast<const float4*>(&s[row][(k4 ^ (row >> 3)) << 2]);
      }
      #pragma unroll
      for (int jj = 0; jj < 8; ++jj) {
        const int row = j0 + jj;
        float4 b4 = *reinterpret_cast<const float4*>(&s[row][(k4 ^ (row >> 3)) << 2]);
        #pragma unroll
        for (int ii = 0; ii < 8; ++ii) {
          acc[ii][jj] += a4[ii].x * b4.x;
          acc[ii][jj] += a4[ii].y * b4.y;
          acc[ii][jj] += a4[ii].z * b4.z;
          acc[ii][jj] += a4[ii].w * b4.w;
        }
      }
    }
    __syncthreads();
  }

  // tree reduce 8 -> 1 (into wave 0)
  if (w >= 4) wr_partial(&P[w - 4][0][0], acc, g, h);
  __syncthreads();
  if (w < 4) rd_accum(&P[w][0][0], acc, g, h);
  __syncthreads();
  if (w == 2) wr_partial(&P[0][0][0], acc, g, h);
  if (w == 3) wr_partial(&P[1][0][0], acc, g, h);
  __syncthreads();
  if (w < 2) rd_accum(&P[w][0][0], acc, g, h);
  __syncthreads();
  if (w == 1) wr_partial(&P[0][0][0], acc, g, h);
  __syncthreads();
  if (w != 0) return;
  rd_accum(&P[0][0][0], acc, g, h);

  // diag then distances (diag exactly 0: d2 = di+di-2*di = 0), store to global
  if (g == h) {
    #pragma unroll
    for (int ii = 0; ii < 8; ++ii) diag[i0 + ii] = acc[ii][ii];
  }
  float* Db = Dg + (size_t)b * NPTS * NPTS;
  #pragma unroll
  for (int ii = 0; ii < 8; ++ii) {
    float di = diag[i0 + ii];
    #pragma unroll
    for (int jq = 0; jq < 2; ++jq) {
      float4 o;
      float* op = &o.x;
      #pragma unroll
      for (int jx = 0; jx < 4; ++jx) {
        int jj = jq * 4 + jx;
        float d2 = di + diag[j0 + jj] - 2.f * acc[ii][jj];
        d2 = fmaxf(d2, 0.f);
        op[jx] = (d2 > 0.f) ? sqrtf(d2) : 0.f;
      }
      *reinterpret_cast<float4*>(Db + ((i0 + ii) << 6) + j0 + (jq << 2)) = o;
    }
  }
}

// ================= kernel B: clustering + loss terms =================
__global__ __launch_bounds__(64) void cluster_kernel(
    const float* __restrict__ Dg,     // [256,64,64]
    const int*   __restrict__ labels, // [256,64]
    float* __restrict__ simS_o, float* __restrict__ disS_o,
    int* __restrict__ simC_o, int* __restrict__ errC_o)
{
  __shared__ __align__(16) float Dw[NPTS][65];
  __shared__ __align__(16) int cls[NPTS];

  const int b = blockIdx.x;
  const int l = threadIdx.x;
  const float* Db = Dg + (size_t)b * NPTS * NPTS;

  // load own row (single wave: ds ops in-order, no barrier needed)
  #pragma unroll
  for (int v = 0; v < 16; ++v) {
    float4 x = *reinterpret_cast<const float4*>(Db + (l << 6) + (v << 2));
    *reinterpret_cast<float4*>(&Dw[l][v << 2]) = x;
  }

  float* Dm = &Dw[0][0];
  int tl = labels[b * NPTS + l];

  // label-equality mask + unique-label count via 8 ballots
  unsigned long long sMask = 0ull;
  int kcnt = 0;
  #pragma unroll
  for (int v = 0; v < 8; ++v) {
    unsigned long long mv = __ballot(tl == v);
    kcnt += (mv != 0ull) ? 1 : 0;
    if (tl == v) sMask = mv;
  }
  int simC = __popcll(sMask);

  // own-row scan: sim/dis sums + row min (strict <: lowest j wins ties)
  float simS = 0.f, disS = 0.f;
  float mval = BIGF; int midx = 0;
  const float* rowp = Dm + l * 65;
  #pragma unroll 8
  for (int j = 0; j < NPTS; ++j) {
    float v = rowp[j];
    bool sim = (sMask >> j) & 1ull;
    simS += sim ? v : 0.f;
    disS += sim ? 0.f : v;
    bool better = (j != l) && (v < mval);
    mval = better ? v : mval;
    midx = better ? j : midx;
  }
  Dm[l * 65 + l] = BIGF;

  unsigned long long actm = ~0ull;
  int cl = l;
  const int merges = NPTS - kcnt;
  #pragma unroll 1
  for (int m = 0; m < merges; ++m) {
    // argmin: min value then lowest lane. flat = l*64+midx, so lowest-flat
    // == lowest row among min-value rows == lowest ballot lane. For the
    // winner row a, midx > a always (else a lower row would hold the min).
    bool act = (actm >> l) & 1ull;
    float vf = act ? mval : BIGF;
    float gmin = minred64(vf);
    unsigned long long win = __ballot(vf == gmin);
    const int a = __ffsll((long long)win) - 1;
    const int bb = __builtin_amdgcn_readlane(midx, a);

    float va = Dm[l * 65 + a];
    float vb = Dm[l * 65 + bb];
    float nr = fminf(va, vb);
    Dm[l * 65 + a] = nr;
    Dm[a * 65 + l] = nr;

    actm &= ~(1ull << bb);
    cl = (cl == bb) ? a : cl;

    bool actrow = ((actm >> l) & 1ull) && (l != a);
    if (actrow) {
      if (midx == bb) midx = a;
      else if (nr == mval && a < midx) midx = a;
    }
    // rescan row a: candidates nr across active lanes != a; winner lane == cj
    float cv = actrow ? nr : BIGF;
    float g2 = minred64(cv);
    unsigned long long w2 = __ballot(cv == g2);
    int cj = __ffsll((long long)w2) - 1;
    if (l == a) { mval = g2; midx = cj; }
  }

  // err count via masks
  cls[l] = cl;
  unsigned long long cMask = 0ull;
  const int4* cp = reinterpret_cast<const int4*>(cls);
  #pragma unroll 4
  for (int jq = 0; jq < 16; ++jq) {
    int4 c4 = cp[jq];
    cMask |= ((unsigned long long)(c4.x == cl)) << (jq * 4 + 0);
    cMask |= ((unsigned long long)(c4.y == cl)) << (jq * 4 + 1);
    cMask |= ((unsigned long long)(c4.z == cl)) << (jq * 4 + 2);
    cMask |= ((unsigned long long)(c4.w == cl)) << (jq * 4 + 3);
  }
  int ec = __popcll(cMask ^ sMask);

  // wave reductions (deterministic butterfly)
  #pragma unroll
  for (int off = 32; off; off >>= 1) {
    simS += __shfl_xor(simS, off);
    disS += __shfl_xor(disS, off);
    simC += __shfl_xor(simC, off);
    ec   += __shfl_xor(ec, off);
  }
  if (l == 0) {
    simS_o[b] = simS; disS_o[b] = disS;
    simC_o[b] = simC; errC_o[b] = ec;
  }
}

__global__ __launch_bounds__(64) void finalize_kernel(
    const float* __restrict__ simS, const float* __restrict__ disS,
    const int* __restrict__ simC, const int* __restrict__ errC,
    float* __restrict__ out)
{
  const int l = threadIdx.x;
  double ss = 0.0, dd = 0.0, sc = 0.0, ec = 0.0;
  #pragma unroll
  for (int r = 0; r < 4; ++r) {
    int i = (r << 6) + l;
    ss += (double)simS[i];
    dd += (double)disS[i];
    sc += (double)simC[i];
    ec += (double)errC[i];
  }
  #pragma unroll
  for (int off = 32; off; off >>= 1) {
    ss += __shfl_xor(ss, off);
    dd += __shfl_xor(dd, off);
    sc += __shfl_xor(sc, off);
    ec += __shfl_xor(ec, off);
  }
  if (l == 0) {
    const double total = 256.0 * 4096.0;
    double ms = ss / sc;
    double md = dd / (total - sc);
    out[0] = (float)(ec / 256.0 + 0.5 * (ms - md));
  }
}

extern "C" void kernel_launch(void* const* d_in, const int* in_sizes, int n_in,
                              void* d_out, int out_size, void* d_ws, size_t ws_size,
                              hipStream_t stream) {
  const float* q      = (const float*)d_in[0];
  const float* psg    = (const float*)d_in[1];
  const int*   labels = (const int*)d_in[2];
  float* out = (float*)d_out;

  float* Dg   = (float*)d_ws;              // [256*64*64] = 4 MB
  float* simS = Dg + 256 * NPTS * NPTS;    // [256]
  float* disS = simS + 256;                // [256]
  int*   simC = (int*)(disS + 256);        // [256]
  int*   errC = simC + 256;                // [256]

  gram_kernel<<<256, NT, 0, stream>>>(q, psg, Dg);
  cluster_kernel<<<256, 64, 0, stream>>>(Dg, labels, simS, disS, simC, errC);
  finalize_kernel<<<1, 64, 0, stream>>>(simS, disS, simC, errC, out);
}

// Round 7
// 67.754 us; speedup vs baseline: 1.4806x; 1.1308x over previous
//
#include <hip/hip_runtime.h>

// QuerySpecificClusterModel: B=256 samples, n=64 points, d=768.
// Round 7: root cause of the persistent spill found by diffing round 1 (104
// VGPR, WRITE 32B) vs rounds 2-6 (128 VGPR, WRITE 40-50MB): round 2 changed
// the kk inner loop from `#pragma unroll 1` to full unroll -> 4 concurrent
// a4[8] fragment arrays (128 VGPRs) + acc (64) >> 128 cap -> scratch spill
// in the hot loop. Restore `#pragma unroll 1` (kk and c loops pinned).
// Everything else identical to round 6's split structure.

#define NPTS 64
#define DIM 768
#define CH 128
#define NCH 6
#define NT 512
#define BIGF 1e9f

// ---- value-only DPP min reduce over 64 lanes, result broadcast ----
template <int CTRL>
__device__ __forceinline__ float vmin_step(float v) {
  int s = __builtin_amdgcn_update_dpp(__float_as_int(v), __float_as_int(v),
                                      CTRL, 0xF, 0xF, false);
  return fminf(v, __int_as_float(s));
}

__device__ __forceinline__ float minred64(float v) {
  v = vmin_step<0x121>(v);   // row_ror:1
  v = vmin_step<0x122>(v);   // row_ror:2
  v = vmin_step<0x124>(v);   // row_ror:4
  v = vmin_step<0x128>(v);   // row_ror:8
  v = vmin_step<0x142>(v);   // row_bcast:15
  v = vmin_step<0x143>(v);   // row_bcast:31
  return __int_as_float(__builtin_amdgcn_readlane(__float_as_int(v), 63));
}

// ---- tree-reduce partial helpers (XOR slot-swizzle: <=4-way conflicts) ----
__device__ __forceinline__ void wr_partial(float* __restrict__ Pb,
                                           const float (&acc)[8][8], int g, int h) {
  #pragma unroll
  for (int ii = 0; ii < 8; ++ii) {
    const int row = (g << 3) + ii;
    #pragma unroll
    for (int jq = 0; jq < 2; ++jq) {
      const int sl = ((h << 1) + jq) ^ g;
      float4 v = make_float4(acc[ii][jq * 4 + 0], acc[ii][jq * 4 + 1],
                             acc[ii][jq * 4 + 2], acc[ii][jq * 4 + 3]);
      *reinterpret_cast<float4*>(Pb + (row << 6) + (sl << 2)) = v;
    }
  }
}

__device__ __forceinline__ void rd_accum(const float* __restrict__ Pb,
                                         float (&acc)[8][8], int g, int h) {
  #pragma unroll
  for (int ii = 0; ii < 8; ++ii) {
    const int row = (g << 3) + ii;
    #pragma unroll
    for (int jq = 0; jq < 2; ++jq) {
      const int sl = ((h << 1) + jq) ^ g;
      float4 v = *reinterpret_cast<const float4*>(Pb + (row << 6) + (sl << 2));
      acc[ii][jq * 4 + 0] += v.x; acc[ii][jq * 4 + 1] += v.y;
      acc[ii][jq * 4 + 2] += v.z; acc[ii][jq * 4 + 3] += v.w;
    }
  }
}

// ================= kernel A: Gram + distance matrix -> d_ws =================
__global__ __launch_bounds__(NT) void gram_kernel(
    const float* __restrict__ q,      // [256,768]
    const float* __restrict__ psg,    // [256,64,768]
    float* __restrict__ Dg)           // [256,64,64]
{
  __shared__ __align__(16) float s[NPTS][132];        // staged scaled chunk
  __shared__ __align__(16) float P[4][NPTS][NPTS];    // tree-reduce scratch
  __shared__ float diag[NPTS];

  const int b = blockIdx.x;
  const int t = threadIdx.x;
  const int w = t >> 6;
  const int lane = t & 63;
  const int g = lane >> 3;
  const int h = lane & 7;
  const int i0 = g << 3;
  const int j0 = h << 3;

  const float* qb = q + (size_t)b * DIM;
  const float* pb = psg + (size_t)b * NPTS * DIM;

  float acc[8][8] = {};

  const int kvq = t & 31;
  const int irb = t >> 5;

  #pragma unroll 1
  for (int c = 0; c < NCH; ++c) {
    float4 qv = *reinterpret_cast<const float4*>(qb + c * CH + (kvq << 2));
    #pragma unroll
    for (int r = 0; r < 4; ++r) {
      const int i = irb + (r << 4);
      float4 pv = *reinterpret_cast<const float4*>(
          pb + (size_t)i * DIM + c * CH + (kvq << 2));
      float4 sv = make_float4(pv.x * qv.x, pv.y * qv.y, pv.z * qv.z, pv.w * qv.w);
      *reinterpret_cast<float4*>(&s[i][(kvq ^ (i >> 3)) << 2]) = sv;
    }
    __syncthreads();
    // KEY: unroll 1 keeps exactly one a4[8] live (32 VGPRs) -> no spill.
    #pragma unroll 1
    for (int kk = 0; kk < 4; ++kk) {
      const int k4 = (w << 2) + kk;
      float4 a4[8];
      #pragma unroll
      for (int ii = 0; ii < 8; ++ii) {
        const int row = i0 + ii;
        a4[ii] = *reinterpret_cast<const float4*>(&s[row][(k4 ^ (row >> 3)) << 2]);
      }
      #pragma unroll
      for (int jj = 0; jj < 8; ++jj) {
        const int row = j0 + jj;
        float4 b4 = *reinterpret_cast<const float4*>(&s[row][(k4 ^ (row >> 3)) << 2]);
        #pragma unroll
        for (int ii = 0; ii < 8; ++ii) {
          acc[ii][jj] += a4[ii].x * b4.x;
          acc[ii][jj] += a4[ii].y * b4.y;
          acc[ii][jj] += a4[ii].z * b4.z;
          acc[ii][jj] += a4[ii].w * b4.w;
        }
      }
    }
    __syncthreads();
  }

  // tree reduce 8 -> 1 (into wave 0)
  if (w >= 4) wr_partial(&P[w - 4][0][0], acc, g, h);
  __syncthreads();
  if (w < 4) rd_accum(&P[w][0][0], acc, g, h);
  __syncthreads();
  if (w == 2) wr_partial(&P[0][0][0], acc, g, h);
  if (w == 3) wr_partial(&P[1][0][0], acc, g, h);
  __syncthreads();
  if (w < 2) rd_accum(&P[w][0][0], acc, g, h);
  __syncthreads();
  if (w == 1) wr_partial(&P[0][0][0], acc, g, h);
  __syncthreads();
  if (w != 0) return;
  rd_accum(&P[0][0][0], acc, g, h);

  // diag then distances (diag exactly 0), store to global
  if (g == h) {
    #pragma unroll
    for (int ii = 0; ii < 8; ++ii) diag[i0 + ii] = acc[ii][ii];
  }
  float* Db = Dg + (size_t)b * NPTS * NPTS;
  #pragma unroll
  for (int ii = 0; ii < 8; ++ii) {
    float di = diag[i0 + ii];
    #pragma unroll
    for (int jq = 0; jq < 2; ++jq) {
      float4 o;
      float* op = &o.x;
      #pragma unroll
      for (int jx = 0; jx < 4; ++jx) {
        int jj = jq * 4 + jx;
        float d2 = di + diag[j0 + jj] - 2.f * acc[ii][jj];
        d2 = fmaxf(d2, 0.f);
        op[jx] = (d2 > 0.f) ? sqrtf(d2) : 0.f;
      }
      *reinterpret_cast<float4*>(Db + ((i0 + ii) << 6) + j0 + (jq << 2)) = o;
    }
  }
}

// ================= kernel B: clustering + loss terms =================
__global__ __launch_bounds__(64) void cluster_kernel(
    const float* __restrict__ Dg,     // [256,64,64]
    const int*   __restrict__ labels, // [256,64]
    float* __restrict__ simS_o, float* __restrict__ disS_o,
    int* __restrict__ simC_o, int* __restrict__ errC_o)
{
  __shared__ __align__(16) float Dw[NPTS][65];
  __shared__ __align__(16) int cls[NPTS];

  const int b = blockIdx.x;
  const int l = threadIdx.x;
  const float* Db = Dg + (size_t)b * NPTS * NPTS;

  // load own row (single wave: ds ops in-order, no barrier needed)
  #pragma unroll
  for (int v = 0; v < 16; ++v) {
    float4 x = *reinterpret_cast<const float4*>(Db + (l << 6) + (v << 2));
    *reinterpret_cast<float4*>(&Dw[l][v << 2]) = x;
  }

  float* Dm = &Dw[0][0];
  int tl = labels[b * NPTS + l];

  // label-equality mask + unique-label count via 8 ballots
  unsigned long long sMask = 0ull;
  int kcnt = 0;
  #pragma unroll
  for (int v = 0; v < 8; ++v) {
    unsigned long long mv = __ballot(tl == v);
    kcnt += (mv != 0ull) ? 1 : 0;
    if (tl == v) sMask = mv;
  }
  int simC = __popcll(sMask);

  // own-row scan: sim/dis sums + row min (strict <: lowest j wins ties)
  float simS = 0.f, disS = 0.f;
  float mval = BIGF; int midx = 0;
  const float* rowp = Dm + l * 65;
  #pragma unroll 8
  for (int j = 0; j < NPTS; ++j) {
    float v = rowp[j];
    bool sim = (sMask >> j) & 1ull;
    simS += sim ? v : 0.f;
    disS += sim ? 0.f : v;
    bool better = (j != l) && (v < mval);
    mval = better ? v : mval;
    midx = better ? j : midx;
  }
  Dm[l * 65 + l] = BIGF;

  unsigned long long actm = ~0ull;
  int cl = l;
  const int merges = NPTS - kcnt;
  #pragma unroll 1
  for (int m = 0; m < merges; ++m) {
    // argmin: min value then lowest lane. flat = l*64+midx, so lowest-flat
    // == lowest row among min-value rows == lowest ballot lane.
    bool act = (actm >> l) & 1ull;
    float vf = act ? mval : BIGF;
    float gmin = minred64(vf);
    unsigned long long win = __ballot(vf == gmin);
    const int a = __ffsll((long long)win) - 1;
    const int bb = __builtin_amdgcn_readlane(midx, a);

    float va = Dm[l * 65 + a];
    float vb = Dm[l * 65 + bb];
    float nr = fminf(va, vb);
    Dm[l * 65 + a] = nr;
    Dm[a * 65 + l] = nr;

    actm &= ~(1ull << bb);
    cl = (cl == bb) ? a : cl;

    bool actrow = ((actm >> l) & 1ull) && (l != a);
    if (actrow) {
      if (midx == bb) midx = a;
      else if (nr == mval && a < midx) midx = a;
    }
    // rescan row a: candidates nr across active lanes != a; winner lane == cj
    float cv = actrow ? nr : BIGF;
    float g2 = minred64(cv);
    unsigned long long w2 = __ballot(cv == g2);
    int cj = __ffsll((long long)w2) - 1;
    if (l == a) { mval = g2; midx = cj; }
  }

  // err count via masks
  cls[l] = cl;
  unsigned long long cMask = 0ull;
  const int4* cp = reinterpret_cast<const int4*>(cls);
  #pragma unroll 4
  for (int jq = 0; jq < 16; ++jq) {
    int4 c4 = cp[jq];
    cMask |= ((unsigned long long)(c4.x == cl)) << (jq * 4 + 0);
    cMask |= ((unsigned long long)(c4.y == cl)) << (jq * 4 + 1);
    cMask |= ((unsigned long long)(c4.z == cl)) << (jq * 4 + 2);
    cMask |= ((unsigned long long)(c4.w == cl)) << (jq * 4 + 3);
  }
  int ec = __popcll(cMask ^ sMask);

  // wave reductions (deterministic butterfly)
  #pragma unroll
  for (int off = 32; off; off >>= 1) {
    simS += __shfl_xor(simS, off);
    disS += __shfl_xor(disS, off);
    simC += __shfl_xor(simC, off);
    ec   += __shfl_xor(ec, off);
  }
  if (l == 0) {
    simS_o[b] = simS; disS_o[b] = disS;
    simC_o[b] = simC; errC_o[b] = ec;
  }
}

__global__ __launch_bounds__(64) void finalize_kernel(
    const float* __restrict__ simS, const float* __restrict__ disS,
    const int* __restrict__ simC, const int* __restrict__ errC,
    float* __restrict__ out)
{
  const int l = threadIdx.x;
  double ss = 0.0, dd = 0.0, sc = 0.0, ec = 0.0;
  #pragma unroll
  for (int r = 0; r < 4; ++r) {
    int i = (r << 6) + l;
    ss += (double)simS[i];
    dd += (double)disS[i];
    sc += (double)simC[i];
    ec += (double)errC[i];
  }
  #pragma unroll
  for (int off = 32; off; off >>= 1) {
    ss += __shfl_xor(ss, off);
    dd += __shfl_xor(dd, off);
    sc += __shfl_xor(sc, off);
    ec += __shfl_xor(ec, off);
  }
  if (l == 0) {
    const double total = 256.0 * 4096.0;
    double ms = ss / sc;
    double md = dd / (total - sc);
    out[0] = (float)(ec / 256.0 + 0.5 * (ms - md));
  }
}

extern "C" void kernel_launch(void* const* d_in, const int* in_sizes, int n_in,
                              void* d_out, int out_size, void* d_ws, size_t ws_size,
                              hipStream_t stream) {
  const float* q      = (const float*)d_in[0];
  const float* psg    = (const float*)d_in[1];
  const int*   labels = (const int*)d_in[2];
  float* out = (float*)d_out;

  float* Dg   = (float*)d_ws;              // [256*64*64] = 4 MB
  float* simS = Dg + 256 * NPTS * NPTS;    // [256]
  float* disS = simS + 256;                // [256]
  int*   simC = (int*)(disS + 256);        // [256]
  int*   errC = simC + 256;                // [256]

  gram_kernel<<<256, NT, 0, stream>>>(q, psg, Dg);
  cluster_kernel<<<256, 64, 0, stream>>>(Dg, labels, simS, disS, simC, errC);
  finalize_kernel<<<1, 64, 0, stream>>>(simS, disS, simC, errC, out);
}

// Round 8
// 46.333 us; speedup vs baseline: 2.1651x; 1.4623x over previous
//
#include <hip/hip_runtime.h>

// QuerySpecificClusterModel: B=256 samples, n=64 points, d=768.
// Round 8: MFMA Gram via exact bf16 triple-split. x = h+m+l (exact: h=bf16(x),
// m=bf16(x-h), l=x-h-m fits 8 bits). G = S.S^T computed as 6 MFMA passes
// (hh,hm,mh,mm,hl,lh) fused in one k-loop; dropped terms <= 2^-24 rel.
// Gram symmetry: B-frag == A-frag (same lane data), halving LDS reads and
// cancelling any k-interleave layout uncertainty. 8 waves = 4 regions(32x32)
// x 2 K-split, pair-reduced in LDS. Cluster/finalize unchanged from round 7.

#define NPTS 64
#define DIM 768
#define CH 128
#define NCH 6
#define NT 512
#define BIGF 1e9f

typedef __attribute__((ext_vector_type(8))) __bf16 bf16x8;
typedef __attribute__((ext_vector_type(4))) float f32x4;
typedef __attribute__((ext_vector_type(8))) unsigned short us8;

// ---- value-only DPP min reduce over 64 lanes, result broadcast ----
template <int CTRL>
__device__ __forceinline__ float vmin_step(float v) {
  int s = __builtin_amdgcn_update_dpp(__float_as_int(v), __float_as_int(v),
                                      CTRL, 0xF, 0xF, false);
  return fminf(v, __int_as_float(s));
}

__device__ __forceinline__ float minred64(float v) {
  v = vmin_step<0x121>(v);   // row_ror:1
  v = vmin_step<0x122>(v);   // row_ror:2
  v = vmin_step<0x124>(v);   // row_ror:4
  v = vmin_step<0x128>(v);   // row_ror:8
  v = vmin_step<0x142>(v);   // row_bcast:15
  v = vmin_step<0x143>(v);   // row_bcast:31
  return __int_as_float(__builtin_amdgcn_readlane(__float_as_int(v), 63));
}

// ---- exact 3-way bf16 split: x == h + m + l (l truncation is exact) ----
__device__ __forceinline__ void split3(float x, unsigned short& h,
                                       unsigned short& m, unsigned short& l) {
  unsigned u = __float_as_uint(x);
  unsigned rb = (u + 0x7FFFu + ((u >> 16) & 1u)) & 0xFFFF0000u;   // RNE
  h = (unsigned short)(rb >> 16);
  float r1 = x - __uint_as_float(rb);                              // exact
  unsigned u1 = __float_as_uint(r1);
  unsigned rb1 = (u1 + 0x7FFFu + ((u1 >> 16) & 1u)) & 0xFFFF0000u;
  m = (unsigned short)(rb1 >> 16);
  float r2 = r1 - __uint_as_float(rb1);                            // exact
  l = (unsigned short)(__float_as_uint(r2) >> 16);                 // exact (<=8 bits)
}

// ================= kernel A: MFMA Gram + distances -> d_ws =================
__global__ __launch_bounds__(NT) void gram_kernel(
    const float* __restrict__ q,      // [256,768]
    const float* __restrict__ psg,    // [256,64,768]
    float* __restrict__ Dg)           // [256,64,64]
{
  __shared__ __align__(16) unsigned short Hml[3][NPTS][CH];  // 48 KB h/m/l bf16
  __shared__ __align__(16) float PG[NPTS * 66];              // Pred then G64[64][66]

  const int b = blockIdx.x;
  const int t = threadIdx.x;
  const int w = t >> 6;
  const int l = t & 63;

  const float* qb = q + (size_t)b * DIM;
  const float* pb = psg + (size_t)b * NPTS * DIM;

  // staging geometry: thread owns granule (8 elems) of rows row0, row0+32
  const int row0 = t >> 4;          // 0..31
  const int gran = t & 15;          // 16B granule within chunk row
  const float* pr0 = pb + (size_t)row0 * DIM + (gran << 3);
  const float* pr1 = pr0 + 32 * DIM;
  const float* qr  = qb + (gran << 3);

  // MFMA geometry: region (R,C) 32x32, K-split ksub
  const int rw = w >> 1;
  const int R = rw >> 1, C = rw & 1;
  const int ksub = w & 1;
  const int lrow = l & 15;

  f32x4 acc[2][2];
  {
    f32x4 z = {0.f, 0.f, 0.f, 0.f};
    acc[0][0] = z; acc[0][1] = z; acc[1][0] = z; acc[1][1] = z;
  }

  float4 pva[2][2], qv[2];
  pva[0][0] = *(const float4*)(pr0 + 0);
  pva[0][1] = *(const float4*)(pr0 + 4);
  pva[1][0] = *(const float4*)(pr1 + 0);
  pva[1][1] = *(const float4*)(pr1 + 4);
  qv[0] = *(const float4*)(qr + 0);
  qv[1] = *(const float4*)(qr + 4);

  #pragma unroll 1
  for (int c = 0; c < NCH; ++c) {
    // convert + swizzled LDS write (chunk c, from prefetched regs)
    #pragma unroll
    for (int rr = 0; rr < 2; ++rr) {
      const int row = row0 + (rr << 5);
      float xs[8];
      xs[0] = pva[rr][0].x * qv[0].x; xs[1] = pva[rr][0].y * qv[0].y;
      xs[2] = pva[rr][0].z * qv[0].z; xs[3] = pva[rr][0].w * qv[0].w;
      xs[4] = pva[rr][1].x * qv[1].x; xs[5] = pva[rr][1].y * qv[1].y;
      xs[6] = pva[rr][1].z * qv[1].z; xs[7] = pva[rr][1].w * qv[1].w;
      us8 uh, um, ul;
      #pragma unroll
      for (int e = 0; e < 8; ++e) {
        unsigned short hh, mm, ll;
        split3(xs[e], hh, mm, ll);
        uh[e] = hh; um[e] = mm; ul[e] = ll;
      }
      const int p = gran ^ (row & 15);          // granule XOR swizzle
      *reinterpret_cast<us8*>(&Hml[0][row][p << 3]) = uh;
      *reinterpret_cast<us8*>(&Hml[1][row][p << 3]) = um;
      *reinterpret_cast<us8*>(&Hml[2][row][p << 3]) = ul;
    }
    // prefetch chunk c+1 (flies during MFMA phase)
    if (c + 1 < NCH) {
      const int off = (c + 1) * CH;
      pva[0][0] = *(const float4*)(pr0 + off);
      pva[0][1] = *(const float4*)(pr0 + off + 4);
      pva[1][0] = *(const float4*)(pr1 + off);
      pva[1][1] = *(const float4*)(pr1 + off + 4);
      qv[0] = *(const float4*)(qr + off);
      qv[1] = *(const float4*)(qr + off + 4);
    }
    __syncthreads();

    // MFMA: this wave's 2 k-steps of this chunk
    #pragma unroll 1
    for (int ss = 0; ss < 2; ++ss) {
      const int s = ksub + (ss << 1);
      const int p = ((s << 2) + (l >> 4)) ^ lrow;  // swizzled granule
      bf16x8 fa[3][2], fb[3][2];
      #pragma unroll
      for (int v = 0; v < 3; ++v)
        #pragma unroll
        for (int tb = 0; tb < 2; ++tb) {
          const int row = (R << 5) + (tb << 4) + lrow;
          fa[v][tb] = *reinterpret_cast<const bf16x8*>(&Hml[v][row][p << 3]);
        }
      if (R != C) {
        #pragma unroll
        for (int v = 0; v < 3; ++v)
          #pragma unroll
          for (int tb = 0; tb < 2; ++tb) {
            const int row = (C << 5) + (tb << 4) + lrow;
            fb[v][tb] = *reinterpret_cast<const bf16x8*>(&Hml[v][row][p << 3]);
          }
      } else {
        #pragma unroll
        for (int v = 0; v < 3; ++v)
          #pragma unroll
          for (int tb = 0; tb < 2; ++tb) fb[v][tb] = fa[v][tb];
      }
      #pragma unroll
      for (int ti = 0; ti < 2; ++ti)
        #pragma unroll
        for (int tj = 0; tj < 2; ++tj) {
          acc[ti][tj] = __builtin_amdgcn_mfma_f32_16x16x32_bf16(fa[0][ti], fb[0][tj], acc[ti][tj], 0, 0, 0); // hh
          acc[ti][tj] = __builtin_amdgcn_mfma_f32_16x16x32_bf16(fa[0][ti], fb[1][tj], acc[ti][tj], 0, 0, 0); // hm
          acc[ti][tj] = __builtin_amdgcn_mfma_f32_16x16x32_bf16(fa[1][ti], fb[0][tj], acc[ti][tj], 0, 0, 0); // mh
          acc[ti][tj] = __builtin_amdgcn_mfma_f32_16x16x32_bf16(fa[1][ti], fb[1][tj], acc[ti][tj], 0, 0, 0); // mm
          acc[ti][tj] = __builtin_amdgcn_mfma_f32_16x16x32_bf16(fa[0][ti], fb[2][tj], acc[ti][tj], 0, 0, 0); // hl
          acc[ti][tj] = __builtin_amdgcn_mfma_f32_16x16x32_bf16(fa[2][ti], fb[0][tj], acc[ti][tj], 0, 0, 0); // lh
        }
    }
    __syncthreads();
  }

  // K-split pair reduce: odd wave -> LDS, even wave adds
  if (w & 1) {
    float* dst = PG + (rw << 10);
    #pragma unroll
    for (int ti = 0; ti < 2; ++ti)
      #pragma unroll
      for (int tj = 0; tj < 2; ++tj)
        *reinterpret_cast<f32x4*>(dst + (((ti << 1) + tj) << 8) + (l << 2)) = acc[ti][tj];
  }
  __syncthreads();
  if (!(w & 1)) {
    const float* src = PG + (rw << 10);
    #pragma unroll
    for (int ti = 0; ti < 2; ++ti)
      #pragma unroll
      for (int tj = 0; tj < 2; ++tj)
        acc[ti][tj] += *reinterpret_cast<const f32x4*>(src + (((ti << 1) + tj) << 8) + (l << 2));
  }
  __syncthreads();
  // even waves scatter G into PG[64][66] (C/D layout: col=l&15, row=4*(l>>4)+reg)
  if (!(w & 1)) {
    #pragma unroll
    for (int ti = 0; ti < 2; ++ti)
      #pragma unroll
      for (int tj = 0; tj < 2; ++tj)
        #pragma unroll
        for (int reg = 0; reg < 4; ++reg) {
          const int grow = (R << 5) + (ti << 4) + ((l >> 4) << 2) + reg;
          const int gcol = (C << 5) + (tj << 4) + (l & 15);
          PG[grow * 66 + gcol] = acc[ti][tj][reg];
        }
  }
  __syncthreads();

  // distances: d2 = G[r][r] + G[c][c] - 2 G[r][c]; diag exactly 0
  const int r  = t >> 3;
  const int c0 = (t & 7) << 3;
  const float dr = PG[r * 66 + r];
  float vout[8];
  #pragma unroll
  for (int e = 0; e < 8; ++e) {
    const int cc = c0 + e;
    const float gg = PG[r * 66 + cc];
    const float dc = PG[cc * 66 + cc];
    float d2 = dr + dc - 2.f * gg;
    d2 = fmaxf(d2, 0.f);
    vout[e] = (d2 > 0.f) ? sqrtf(d2) : 0.f;
  }
  float* Db = Dg + (size_t)b * NPTS * NPTS;
  *(float4*)(Db + (r << 6) + c0)     = make_float4(vout[0], vout[1], vout[2], vout[3]);
  *(float4*)(Db + (r << 6) + c0 + 4) = make_float4(vout[4], vout[5], vout[6], vout[7]);
}

// ================= kernel B: clustering + loss terms (round-7) =============
__global__ __launch_bounds__(64) void cluster_kernel(
    const float* __restrict__ Dg,     // [256,64,64]
    const int*   __restrict__ labels, // [256,64]
    float* __restrict__ simS_o, float* __restrict__ disS_o,
    int* __restrict__ simC_o, int* __restrict__ errC_o)
{
  __shared__ __align__(16) float Dw[NPTS][65];
  __shared__ __align__(16) int cls[NPTS];

  const int b = blockIdx.x;
  const int l = threadIdx.x;
  const float* Db = Dg + (size_t)b * NPTS * NPTS;

  #pragma unroll
  for (int v = 0; v < 16; ++v) {
    float4 x = *reinterpret_cast<const float4*>(Db + (l << 6) + (v << 2));
    *reinterpret_cast<float4*>(&Dw[l][v << 2]) = x;
  }

  float* Dm = &Dw[0][0];
  int tl = labels[b * NPTS + l];

  unsigned long long sMask = 0ull;
  int kcnt = 0;
  #pragma unroll
  for (int v = 0; v < 8; ++v) {
    unsigned long long mv = __ballot(tl == v);
    kcnt += (mv != 0ull) ? 1 : 0;
    if (tl == v) sMask = mv;
  }
  int simC = __popcll(sMask);

  float simS = 0.f, disS = 0.f;
  float mval = BIGF; int midx = 0;
  const float* rowp = Dm + l * 65;
  #pragma unroll 8
  for (int j = 0; j < NPTS; ++j) {
    float v = rowp[j];
    bool sim = (sMask >> j) & 1ull;
    simS += sim ? v : 0.f;
    disS += sim ? 0.f : v;
    bool better = (j != l) && (v < mval);
    mval = better ? v : mval;
    midx = better ? j : midx;
  }
  Dm[l * 65 + l] = BIGF;

  unsigned long long actm = ~0ull;
  int cl = l;
  const int merges = NPTS - kcnt;
  #pragma unroll 1
  for (int m = 0; m < merges; ++m) {
    bool act = (actm >> l) & 1ull;
    float vf = act ? mval : BIGF;
    float gmin = minred64(vf);
    unsigned long long win = __ballot(vf == gmin);
    const int a = __ffsll((long long)win) - 1;
    const int bb = __builtin_amdgcn_readlane(midx, a);

    float va = Dm[l * 65 + a];
    float vb = Dm[l * 65 + bb];
    float nr = fminf(va, vb);
    Dm[l * 65 + a] = nr;
    Dm[a * 65 + l] = nr;

    actm &= ~(1ull << bb);
    cl = (cl == bb) ? a : cl;

    bool actrow = ((actm >> l) & 1ull) && (l != a);
    if (actrow) {
      if (midx == bb) midx = a;
      else if (nr == mval && a < midx) midx = a;
    }
    float cv = actrow ? nr : BIGF;
    float g2 = minred64(cv);
    unsigned long long w2 = __ballot(cv == g2);
    int cj = __ffsll((long long)w2) - 1;
    if (l == a) { mval = g2; midx = cj; }
  }

  cls[l] = cl;
  unsigned long long cMask = 0ull;
  const int4* cp = reinterpret_cast<const int4*>(cls);
  #pragma unroll 4
  for (int jq = 0; jq < 16; ++jq) {
    int4 c4 = cp[jq];
    cMask |= ((unsigned long long)(c4.x == cl)) << (jq * 4 + 0);
    cMask |= ((unsigned long long)(c4.y == cl)) << (jq * 4 + 1);
    cMask |= ((unsigned long long)(c4.z == cl)) << (jq * 4 + 2);
    cMask |= ((unsigned long long)(c4.w == cl)) << (jq * 4 + 3);
  }
  int ec = __popcll(cMask ^ sMask);

  #pragma unroll
  for (int off = 32; off; off >>= 1) {
    simS += __shfl_xor(simS, off);
    disS += __shfl_xor(disS, off);
    simC += __shfl_xor(simC, off);
    ec   += __shfl_xor(ec, off);
  }
  if (l == 0) {
    simS_o[b] = simS; disS_o[b] = disS;
    simC_o[b] = simC; errC_o[b] = ec;
  }
}

__global__ __launch_bounds__(64) void finalize_kernel(
    const float* __restrict__ simS, const float* __restrict__ disS,
    const int* __restrict__ simC, const int* __restrict__ errC,
    float* __restrict__ out)
{
  const int l = threadIdx.x;
  double ss = 0.0, dd = 0.0, sc = 0.0, ec = 0.0;
  #pragma unroll
  for (int r = 0; r < 4; ++r) {
    int i = (r << 6) + l;
    ss += (double)simS[i];
    dd += (double)disS[i];
    sc += (double)simC[i];
    ec += (double)errC[i];
  }
  #pragma unroll
  for (int off = 32; off; off >>= 1) {
    ss += __shfl_xor(ss, off);
    dd += __shfl_xor(dd, off);
    sc += __shfl_xor(sc, off);
    ec += __shfl_xor(ec, off);
  }
  if (l == 0) {
    const double total = 256.0 * 4096.0;
    double ms = ss / sc;
    double md = dd / (total - sc);
    out[0] = (float)(ec / 256.0 + 0.5 * (ms - md));
  }
}

extern "C" void kernel_launch(void* const* d_in, const int* in_sizes, int n_in,
                              void* d_out, int out_size, void* d_ws, size_t ws_size,
                              hipStream_t stream) {
  const float* q      = (const float*)d_in[0];
  const float* psg    = (const float*)d_in[1];
  const int*   labels = (const int*)d_in[2];
  float* out = (float*)d_out;

  float* Dg   = (float*)d_ws;              // [256*64*64] = 4 MB
  float* simS = Dg + 256 * NPTS * NPTS;    // [256]
  float* disS = simS + 256;                // [256]
  int*   simC = (int*)(disS + 256);        // [256]
  int*   errC = simC + 256;                // [256]

  gram_kernel<<<256, NT, 0, stream>>>(q, psg, Dg);
  cluster_kernel<<<256, 64, 0, stream>>>(Dg, labels, simS, disS, simC, errC);
  finalize_kernel<<<1, 64, 0, stream>>>(simS, disS, simC, errC, out);
}

// Round 9
// 43.454 us; speedup vs baseline: 2.3086x; 1.0663x over previous
//
#include <hip/hip_runtime.h>

// QuerySpecificClusterModel: B=256 samples, n=64 points, d=768.
// Round 9: re-fuse clustering into the MFMA gram kernel (distances stay in
// LDS; kills the 4MB Dg roundtrip + cluster row-reload + one launch) and
// double-buffer the Hml staging (1 barrier/chunk; convert-VALU overlaps MFMA
// on separate pipes). Liveness discipline kept: unroll 1 on c/ss loops
// (round-7 lesson: full unroll of fragment loops -> scratch spill).

#define NPTS 64
#define DIM 768
#define CH 128
#define NCH 6
#define NT 512
#define BIGF 1e9f

typedef __attribute__((ext_vector_type(8))) __bf16 bf16x8;
typedef __attribute__((ext_vector_type(4))) float f32x4;
typedef __attribute__((ext_vector_type(8))) unsigned short us8;

// ---- value-only DPP min reduce over 64 lanes, result broadcast ----
template <int CTRL>
__device__ __forceinline__ float vmin_step(float v) {
  int s = __builtin_amdgcn_update_dpp(__float_as_int(v), __float_as_int(v),
                                      CTRL, 0xF, 0xF, false);
  return fminf(v, __int_as_float(s));
}

__device__ __forceinline__ float minred64(float v) {
  v = vmin_step<0x121>(v);   // row_ror:1
  v = vmin_step<0x122>(v);   // row_ror:2
  v = vmin_step<0x124>(v);   // row_ror:4
  v = vmin_step<0x128>(v);   // row_ror:8
  v = vmin_step<0x142>(v);   // row_bcast:15
  v = vmin_step<0x143>(v);   // row_bcast:31
  return __int_as_float(__builtin_amdgcn_readlane(__float_as_int(v), 63));
}

// ---- exact 3-way bf16 split: x == h + m + l ----
__device__ __forceinline__ void split3(float x, unsigned short& h,
                                       unsigned short& m, unsigned short& l) {
  unsigned u = __float_as_uint(x);
  unsigned rb = (u + 0x7FFFu + ((u >> 16) & 1u)) & 0xFFFF0000u;   // RNE
  h = (unsigned short)(rb >> 16);
  float r1 = x - __uint_as_float(rb);                              // exact
  unsigned u1 = __float_as_uint(r1);
  unsigned rb1 = (u1 + 0x7FFFu + ((u1 >> 16) & 1u)) & 0xFFFF0000u;
  m = (unsigned short)(rb1 >> 16);
  float r2 = r1 - __uint_as_float(rb1);                            // exact
  l = (unsigned short)(__float_as_uint(r2) >> 16);                 // exact
}

// ============ fused kernel: MFMA Gram -> distances -> clustering ============
__global__ __launch_bounds__(NT) void fused_kernel(
    const float* __restrict__ q,      // [256,768]
    const float* __restrict__ psg,    // [256,64,768]
    const int*   __restrict__ labels, // [256,64]
    float* __restrict__ simS_o, float* __restrict__ disS_o,
    int* __restrict__ simC_o, int* __restrict__ errC_o)
{
  __shared__ __align__(16) unsigned short Hml[2][3][NPTS][CH]; // 96 KB dbuf
  __shared__ __align__(16) float PG[NPTS * 66];                // G then D
  __shared__ float diagf[NPTS];
  __shared__ __align__(16) int cls[NPTS];

  const int b = blockIdx.x;
  const int t = threadIdx.x;
  const int w = t >> 6;
  const int l = t & 63;

  const float* qb = q + (size_t)b * DIM;
  const float* pb = psg + (size_t)b * NPTS * DIM;

  // staging geometry: thread owns granule (8 elems) of rows row0, row0+32
  const int row0 = t >> 4;
  const int gran = t & 15;
  const float* pr0 = pb + (size_t)row0 * DIM + (gran << 3);
  const float* pr1 = pr0 + 32 * DIM;
  const float* qr  = qb + (gran << 3);

  // MFMA geometry
  const int rw = w >> 1;
  const int R = rw >> 1, C = rw & 1;
  const int ksub = w & 1;
  const int lrow = l & 15;

  f32x4 acc[2][2];
  {
    f32x4 z = {0.f, 0.f, 0.f, 0.f};
    acc[0][0] = z; acc[0][1] = z; acc[1][0] = z; acc[1][1] = z;
  }

  float4 pva[2][2], qv[2];
  pva[0][0] = *(const float4*)(pr0 + 0);
  pva[0][1] = *(const float4*)(pr0 + 4);
  pva[1][0] = *(const float4*)(pr1 + 0);
  pva[1][1] = *(const float4*)(pr1 + 4);
  qv[0] = *(const float4*)(qr + 0);
  qv[1] = *(const float4*)(qr + 4);

  // stage chunk 0 into buf 0
  #pragma unroll
  for (int rr = 0; rr < 2; ++rr) {
    const int row = row0 + (rr << 5);
    float xs[8];
    xs[0] = pva[rr][0].x * qv[0].x; xs[1] = pva[rr][0].y * qv[0].y;
    xs[2] = pva[rr][0].z * qv[0].z; xs[3] = pva[rr][0].w * qv[0].w;
    xs[4] = pva[rr][1].x * qv[1].x; xs[5] = pva[rr][1].y * qv[1].y;
    xs[6] = pva[rr][1].z * qv[1].z; xs[7] = pva[rr][1].w * qv[1].w;
    us8 uh, um, ul;
    #pragma unroll
    for (int e = 0; e < 8; ++e) {
      unsigned short hh, mm, ll;
      split3(xs[e], hh, mm, ll);
      uh[e] = hh; um[e] = mm; ul[e] = ll;
    }
    const int p = gran ^ (row & 15);
    *reinterpret_cast<us8*>(&Hml[0][0][row][p << 3]) = uh;
    *reinterpret_cast<us8*>(&Hml[0][1][row][p << 3]) = um;
    *reinterpret_cast<us8*>(&Hml[0][2][row][p << 3]) = ul;
  }
  __syncthreads();

  #pragma unroll 1
  for (int c = 0; c < NCH; ++c) {
    const int cur = c & 1;
    // issue global prefetch of chunk c+1 (latency hides under MFMA phase)
    if (c + 1 < NCH) {
      const int off = (c + 1) * CH;
      pva[0][0] = *(const float4*)(pr0 + off);
      pva[0][1] = *(const float4*)(pr0 + off + 4);
      pva[1][0] = *(const float4*)(pr1 + off);
      pva[1][1] = *(const float4*)(pr1 + off + 4);
      qv[0] = *(const float4*)(qr + off);
      qv[1] = *(const float4*)(qr + off + 4);
    }

    // MFMA: this wave's 2 k-steps of chunk c (buf cur)
    #pragma unroll 1
    for (int ss = 0; ss < 2; ++ss) {
      const int s = ksub + (ss << 1);
      const int p = ((s << 2) + (l >> 4)) ^ lrow;
      bf16x8 fa[3][2], fb[3][2];
      #pragma unroll
      for (int v = 0; v < 3; ++v)
        #pragma unroll
        for (int tb = 0; tb < 2; ++tb) {
          const int row = (R << 5) + (tb << 4) + lrow;
          fa[v][tb] = *reinterpret_cast<const bf16x8*>(&Hml[cur][v][row][p << 3]);
        }
      if (R != C) {
        #pragma unroll
        for (int v = 0; v < 3; ++v)
          #pragma unroll
          for (int tb = 0; tb < 2; ++tb) {
            const int row = (C << 5) + (tb << 4) + lrow;
            fb[v][tb] = *reinterpret_cast<const bf16x8*>(&Hml[cur][v][row][p << 3]);
          }
      } else {
        #pragma unroll
        for (int v = 0; v < 3; ++v)
          #pragma unroll
          for (int tb = 0; tb < 2; ++tb) fb[v][tb] = fa[v][tb];
      }
      #pragma unroll
      for (int ti = 0; ti < 2; ++ti)
        #pragma unroll
        for (int tj = 0; tj < 2; ++tj) {
          acc[ti][tj] = __builtin_amdgcn_mfma_f32_16x16x32_bf16(fa[0][ti], fb[0][tj], acc[ti][tj], 0, 0, 0); // hh
          acc[ti][tj] = __builtin_amdgcn_mfma_f32_16x16x32_bf16(fa[0][ti], fb[1][tj], acc[ti][tj], 0, 0, 0); // hm
          acc[ti][tj] = __builtin_amdgcn_mfma_f32_16x16x32_bf16(fa[1][ti], fb[0][tj], acc[ti][tj], 0, 0, 0); // mh
          acc[ti][tj] = __builtin_amdgcn_mfma_f32_16x16x32_bf16(fa[1][ti], fb[1][tj], acc[ti][tj], 0, 0, 0); // mm
          acc[ti][tj] = __builtin_amdgcn_mfma_f32_16x16x32_bf16(fa[0][ti], fb[2][tj], acc[ti][tj], 0, 0, 0); // hl
          acc[ti][tj] = __builtin_amdgcn_mfma_f32_16x16x32_bf16(fa[2][ti], fb[0][tj], acc[ti][tj], 0, 0, 0); // lh
        }
    }

    // stage chunk c+1 into the other buffer (no readers there this iter)
    if (c + 1 < NCH) {
      #pragma unroll
      for (int rr = 0; rr < 2; ++rr) {
        const int row = row0 + (rr << 5);
        float xs[8];
        xs[0] = pva[rr][0].x * qv[0].x; xs[1] = pva[rr][0].y * qv[0].y;
        xs[2] = pva[rr][0].z * qv[0].z; xs[3] = pva[rr][0].w * qv[0].w;
        xs[4] = pva[rr][1].x * qv[1].x; xs[5] = pva[rr][1].y * qv[1].y;
        xs[6] = pva[rr][1].z * qv[1].z; xs[7] = pva[rr][1].w * qv[1].w;
        us8 uh, um, ul;
        #pragma unroll
        for (int e = 0; e < 8; ++e) {
          unsigned short hh, mm, ll;
          split3(xs[e], hh, mm, ll);
          uh[e] = hh; um[e] = mm; ul[e] = ll;
        }
        const int p = gran ^ (row & 15);
        *reinterpret_cast<us8*>(&Hml[cur ^ 1][0][row][p << 3]) = uh;
        *reinterpret_cast<us8*>(&Hml[cur ^ 1][1][row][p << 3]) = um;
        *reinterpret_cast<us8*>(&Hml[cur ^ 1][2][row][p << 3]) = ul;
      }
    }
    __syncthreads();
  }

  // ---- K-split pair reduce: odd wave -> LDS, even wave adds ----
  if (w & 1) {
    float* dst = PG + (rw << 10);
    #pragma unroll
    for (int ti = 0; ti < 2; ++ti)
      #pragma unroll
      for (int tj = 0; tj < 2; ++tj)
        *reinterpret_cast<f32x4*>(dst + (((ti << 1) + tj) << 8) + (l << 2)) = acc[ti][tj];
  }
  __syncthreads();
  if (!(w & 1)) {
    const float* src = PG + (rw << 10);
    #pragma unroll
    for (int ti = 0; ti < 2; ++ti)
      #pragma unroll
      for (int tj = 0; tj < 2; ++tj)
        acc[ti][tj] += *reinterpret_cast<const f32x4*>(src + (((ti << 1) + tj) << 8) + (l << 2));
  }
  __syncthreads();
  // even waves scatter G into PG[64][66] (C/D layout: col=l&15, row=4*(l>>4)+reg)
  if (!(w & 1)) {
    #pragma unroll
    for (int ti = 0; ti < 2; ++ti)
      #pragma unroll
      for (int tj = 0; tj < 2; ++tj)
        #pragma unroll
        for (int reg = 0; reg < 4; ++reg) {
          const int grow = (R << 5) + (ti << 4) + ((l >> 4) << 2) + reg;
          const int gcol = (C << 5) + (tj << 4) + (l & 15);
          PG[grow * 66 + gcol] = acc[ti][tj][reg];
        }
  }
  __syncthreads();

  // ---- distances in place: extract diag, then overwrite G with D ----
  if (t < NPTS) diagf[t] = PG[t * 66 + t];
  __syncthreads();
  {
    const int r  = t >> 3;
    const int c0 = (t & 7) << 3;
    const float dr = diagf[r];
    #pragma unroll
    for (int e = 0; e < 8; ++e) {
      const int cc = c0 + e;
      const float gg = PG[r * 66 + cc];     // read G (only this thread uses it)
      float d2 = dr + diagf[cc] - 2.f * gg;
      d2 = fmaxf(d2, 0.f);
      PG[r * 66 + cc] = (d2 > 0.f) ? sqrtf(d2) : 0.f;
    }
  }
  __syncthreads();
  if (w != 0) return;            // wave 0 runs clustering; same-wave LDS in-order

  // ---------------- clustering (single wave, lane l owns row l) -------------
  float* Dm = PG;                // stride 66
  int tl = labels[b * NPTS + l];

  unsigned long long sMask = 0ull;
  int kcnt = 0;
  #pragma unroll
  for (int v = 0; v < 8; ++v) {
    unsigned long long mv = __ballot(tl == v);
    kcnt += (mv != 0ull) ? 1 : 0;
    if (tl == v) sMask = mv;
  }
  int simC = __popcll(sMask);

  float simS = 0.f, disS = 0.f;
  float mval = BIGF; int midx = 0;
  const float* rowp = Dm + l * 66;
  #pragma unroll 8
  for (int j = 0; j < NPTS; ++j) {
    float v = rowp[j];
    bool sim = (sMask >> j) & 1ull;
    simS += sim ? v : 0.f;
    disS += sim ? 0.f : v;
    bool better = (j != l) && (v < mval);
    mval = better ? v : mval;
    midx = better ? j : midx;
  }
  Dm[l * 66 + l] = BIGF;

  unsigned long long actm = ~0ull;
  int cl = l;
  const int merges = NPTS - kcnt;
  #pragma unroll 1
  for (int m = 0; m < merges; ++m) {
    // argmin: min value then lowest lane (== lowest flat index)
    bool act = (actm >> l) & 1ull;
    float vf = act ? mval : BIGF;
    float gmin = minred64(vf);
    unsigned long long win = __ballot(vf == gmin);
    const int a = __ffsll((long long)win) - 1;
    const int bb = __builtin_amdgcn_readlane(midx, a);

    float va = Dm[l * 66 + a];
    float vb = Dm[l * 66 + bb];
    float nr = fminf(va, vb);
    Dm[l * 66 + a] = nr;
    Dm[a * 66 + l] = nr;

    actm &= ~(1ull << bb);
    cl = (cl == bb) ? a : cl;

    bool actrow = ((actm >> l) & 1ull) && (l != a);
    if (actrow) {
      if (midx == bb) midx = a;
      else if (nr == mval && a < midx) midx = a;
    }
    float cv = actrow ? nr : BIGF;
    float g2 = minred64(cv);
    unsigned long long w2 = __ballot(cv == g2);
    int cj = __ffsll((long long)w2) - 1;
    if (l == a) { mval = g2; midx = cj; }
  }

  // err count via masks
  cls[l] = cl;
  unsigned long long cMask = 0ull;
  const int4* cp = reinterpret_cast<const int4*>(cls);
  #pragma unroll 4
  for (int jq = 0; jq < 16; ++jq) {
    int4 c4 = cp[jq];
    cMask |= ((unsigned long long)(c4.x == cl)) << (jq * 4 + 0);
    cMask |= ((unsigned long long)(c4.y == cl)) << (jq * 4 + 1);
    cMask |= ((unsigned long long)(c4.z == cl)) << (jq * 4 + 2);
    cMask |= ((unsigned long long)(c4.w == cl)) << (jq * 4 + 3);
  }
  int ec = __popcll(cMask ^ sMask);

  #pragma unroll
  for (int off = 32; off; off >>= 1) {
    simS += __shfl_xor(simS, off);
    disS += __shfl_xor(disS, off);
    simC += __shfl_xor(simC, off);
    ec   += __shfl_xor(ec, off);
  }
  if (l == 0) {
    simS_o[b] = simS; disS_o[b] = disS;
    simC_o[b] = simC; errC_o[b] = ec;
  }
}

__global__ __launch_bounds__(64) void finalize_kernel(
    const float* __restrict__ simS, const float* __restrict__ disS,
    const int* __restrict__ simC, const int* __restrict__ errC,
    float* __restrict__ out)
{
  const int l = threadIdx.x;
  double ss = 0.0, dd = 0.0, sc = 0.0, ec = 0.0;
  #pragma unroll
  for (int r = 0; r < 4; ++r) {
    int i = (r << 6) + l;
    ss += (double)simS[i];
    dd += (double)disS[i];
    sc += (double)simC[i];
    ec += (double)errC[i];
  }
  #pragma unroll
  for (int off = 32; off; off >>= 1) {
    ss += __shfl_xor(ss, off);
    dd += __shfl_xor(dd, off);
    sc += __shfl_xor(sc, off);
    ec += __shfl_xor(ec, off);
  }
  if (l == 0) {
    const double total = 256.0 * 4096.0;
    double ms = ss / sc;
    double md = dd / (total - sc);
    out[0] = (float)(ec / 256.0 + 0.5 * (ms - md));
  }
}

extern "C" void kernel_launch(void* const* d_in, const int* in_sizes, int n_in,
                              void* d_out, int out_size, void* d_ws, size_t ws_size,
                              hipStream_t stream) {
  const float* q      = (const float*)d_in[0];
  const float* psg    = (const float*)d_in[1];
  const int*   labels = (const int*)d_in[2];
  float* out = (float*)d_out;

  float* simS = (float*)d_ws;          // [256]
  float* disS = simS + 256;            // [256]
  int*   simC = (int*)(disS + 256);    // [256]
  int*   errC = simC + 256;            // [256]

  fused_kernel<<<256, NT, 0, stream>>>(q, psg, labels, simS, disS, simC, errC);
  finalize_kernel<<<1, 64, 0, stream>>>(simS, disS, simC, errC, out);
}

// Round 10
// 36.534 us; speedup vs baseline: 2.7458x; 1.1894x over previous
//
#include <hip/hip_runtime.h>

// QuerySpecificClusterModel: B=256 samples, n=64 points, d=768.
// Round 10: replace the O(n) serial merge loop (57 dependent argmin steps,
// ~28us by occupancy algebra) with Boruvka MST (6 parallel rounds) + edge-rank
// selection + label propagation. Single-linkage at k clusters == components of
// the (64-k) smallest MST edges (Gower-Ross). Distance row lives in REGISTERS
// (never modified -> no dynamic indexing). Per-comp min via 2-stage LDS
// atomicMin (w bits, then flat) = exact lex tie-break. Gram phase = round 9
// (MFMA bf16 triple-split, double-buffered staging).

#define NPTS 64
#define DIM 768
#define CH 128
#define NCH 6
#define NT 512
#define BIGF 1e9f
#define PGS 68   // PG row stride (16B-aligned rows: 68*4=272)

typedef __attribute__((ext_vector_type(8))) __bf16 bf16x8;
typedef __attribute__((ext_vector_type(4))) float f32x4;
typedef __attribute__((ext_vector_type(8))) unsigned short us8;

// cross-lane LDS visibility fence within one wave (guide rule #18)
__device__ __forceinline__ void lds_fence() {
  asm volatile("s_waitcnt lgkmcnt(0)" ::: "memory");
  __builtin_amdgcn_sched_barrier(0);
}

// ---- exact 3-way bf16 split: x == h + m + l ----
__device__ __forceinline__ void split3(float x, unsigned short& h,
                                       unsigned short& m, unsigned short& l) {
  unsigned u = __float_as_uint(x);
  unsigned rb = (u + 0x7FFFu + ((u >> 16) & 1u)) & 0xFFFF0000u;   // RNE
  h = (unsigned short)(rb >> 16);
  float r1 = x - __uint_as_float(rb);                              // exact
  unsigned u1 = __float_as_uint(r1);
  unsigned rb1 = (u1 + 0x7FFFu + ((u1 >> 16) & 1u)) & 0xFFFF0000u;
  m = (unsigned short)(rb1 >> 16);
  float r2 = r1 - __uint_as_float(rb1);                            // exact
  l = (unsigned short)(__float_as_uint(r2) >> 16);                 // exact
}

// ============ fused kernel: MFMA Gram -> distances -> MST clustering ========
__global__ __launch_bounds__(NT) void fused_kernel(
    const float* __restrict__ q,      // [256,768]
    const float* __restrict__ psg,    // [256,64,768]
    const int*   __restrict__ labels, // [256,64]
    float* __restrict__ simS_o, float* __restrict__ disS_o,
    int* __restrict__ simC_o, int* __restrict__ errC_o)
{
  __shared__ __align__(16) unsigned short Hml[2][3][NPTS][CH]; // 96 KB dbuf
  __shared__ __align__(16) float PG[NPTS * PGS];               // G then D
  __shared__ float diagf[NPTS];
  __shared__ __align__(16) int cls[NPTS];
  // MST scratch
  __shared__ __align__(16) int comp_s[NPTS];
  __shared__ unsigned bw_s[NPTS], bfl_s[NPTS];
  __shared__ int ptr_s[NPTS], lab_s[NPTS];
  __shared__ __align__(8) unsigned long long ekey_s[NPTS];
  __shared__ int ecnt_s;

  const int b = blockIdx.x;
  const int t = threadIdx.x;
  const int w = t >> 6;
  const int l = t & 63;

  const float* qb = q + (size_t)b * DIM;
  const float* pb = psg + (size_t)b * NPTS * DIM;

  const int row0 = t >> 4;
  const int gran = t & 15;
  const float* pr0 = pb + (size_t)row0 * DIM + (gran << 3);
  const float* pr1 = pr0 + 32 * DIM;
  const float* qr  = qb + (gran << 3);

  const int rw = w >> 1;
  const int R = rw >> 1, C = rw & 1;
  const int ksub = w & 1;
  const int lrow = l & 15;

  f32x4 acc[2][2];
  {
    f32x4 z = {0.f, 0.f, 0.f, 0.f};
    acc[0][0] = z; acc[0][1] = z; acc[1][0] = z; acc[1][1] = z;
  }

  float4 pva[2][2], qv[2];
  pva[0][0] = *(const float4*)(pr0 + 0);
  pva[0][1] = *(const float4*)(pr0 + 4);
  pva[1][0] = *(const float4*)(pr1 + 0);
  pva[1][1] = *(const float4*)(pr1 + 4);
  qv[0] = *(const float4*)(qr + 0);
  qv[1] = *(const float4*)(qr + 4);

  // stage chunk 0 into buf 0
  #pragma unroll
  for (int rr = 0; rr < 2; ++rr) {
    const int row = row0 + (rr << 5);
    float xs[8];
    xs[0] = pva[rr][0].x * qv[0].x; xs[1] = pva[rr][0].y * qv[0].y;
    xs[2] = pva[rr][0].z * qv[0].z; xs[3] = pva[rr][0].w * qv[0].w;
    xs[4] = pva[rr][1].x * qv[1].x; xs[5] = pva[rr][1].y * qv[1].y;
    xs[6] = pva[rr][1].z * qv[1].z; xs[7] = pva[rr][1].w * qv[1].w;
    us8 uh, um, ul;
    #pragma unroll
    for (int e = 0; e < 8; ++e) {
      unsigned short hh, mm, ll;
      split3(xs[e], hh, mm, ll);
      uh[e] = hh; um[e] = mm; ul[e] = ll;
    }
    const int p = gran ^ (row & 15);
    *reinterpret_cast<us8*>(&Hml[0][0][row][p << 3]) = uh;
    *reinterpret_cast<us8*>(&Hml[0][1][row][p << 3]) = um;
    *reinterpret_cast<us8*>(&Hml[0][2][row][p << 3]) = ul;
  }
  __syncthreads();

  #pragma unroll 1
  for (int c = 0; c < NCH; ++c) {
    const int cur = c & 1;
    if (c + 1 < NCH) {
      const int off = (c + 1) * CH;
      pva[0][0] = *(const float4*)(pr0 + off);
      pva[0][1] = *(const float4*)(pr0 + off + 4);
      pva[1][0] = *(const float4*)(pr1 + off);
      pva[1][1] = *(const float4*)(pr1 + off + 4);
      qv[0] = *(const float4*)(qr + off);
      qv[1] = *(const float4*)(qr + off + 4);
    }

    #pragma unroll 1
    for (int ss = 0; ss < 2; ++ss) {
      const int s = ksub + (ss << 1);
      const int p = ((s << 2) + (l >> 4)) ^ lrow;
      bf16x8 fa[3][2], fb[3][2];
      #pragma unroll
      for (int v = 0; v < 3; ++v)
        #pragma unroll
        for (int tb = 0; tb < 2; ++tb) {
          const int row = (R << 5) + (tb << 4) + lrow;
          fa[v][tb] = *reinterpret_cast<const bf16x8*>(&Hml[cur][v][row][p << 3]);
        }
      if (R != C) {
        #pragma unroll
        for (int v = 0; v < 3; ++v)
          #pragma unroll
          for (int tb = 0; tb < 2; ++tb) {
            const int row = (C << 5) + (tb << 4) + lrow;
            fb[v][tb] = *reinterpret_cast<const bf16x8*>(&Hml[cur][v][row][p << 3]);
          }
      } else {
        #pragma unroll
        for (int v = 0; v < 3; ++v)
          #pragma unroll
          for (int tb = 0; tb < 2; ++tb) fb[v][tb] = fa[v][tb];
      }
      #pragma unroll
      for (int ti = 0; ti < 2; ++ti)
        #pragma unroll
        for (int tj = 0; tj < 2; ++tj) {
          acc[ti][tj] = __builtin_amdgcn_mfma_f32_16x16x32_bf16(fa[0][ti], fb[0][tj], acc[ti][tj], 0, 0, 0); // hh
          acc[ti][tj] = __builtin_amdgcn_mfma_f32_16x16x32_bf16(fa[0][ti], fb[1][tj], acc[ti][tj], 0, 0, 0); // hm
          acc[ti][tj] = __builtin_amdgcn_mfma_f32_16x16x32_bf16(fa[1][ti], fb[0][tj], acc[ti][tj], 0, 0, 0); // mh
          acc[ti][tj] = __builtin_amdgcn_mfma_f32_16x16x32_bf16(fa[1][ti], fb[1][tj], acc[ti][tj], 0, 0, 0); // mm
          acc[ti][tj] = __builtin_amdgcn_mfma_f32_16x16x32_bf16(fa[0][ti], fb[2][tj], acc[ti][tj], 0, 0, 0); // hl
          acc[ti][tj] = __builtin_amdgcn_mfma_f32_16x16x32_bf16(fa[2][ti], fb[0][tj], acc[ti][tj], 0, 0, 0); // lh
        }
    }

    if (c + 1 < NCH) {
      #pragma unroll
      for (int rr = 0; rr < 2; ++rr) {
        const int row = row0 + (rr << 5);
        float xs[8];
        xs[0] = pva[rr][0].x * qv[0].x; xs[1] = pva[rr][0].y * qv[0].y;
        xs[2] = pva[rr][0].z * qv[0].z; xs[3] = pva[rr][0].w * qv[0].w;
        xs[4] = pva[rr][1].x * qv[1].x; xs[5] = pva[rr][1].y * qv[1].y;
        xs[6] = pva[rr][1].z * qv[1].z; xs[7] = pva[rr][1].w * qv[1].w;
        us8 uh, um, ul;
        #pragma unroll
        for (int e = 0; e < 8; ++e) {
          unsigned short hh, mm, ll;
          split3(xs[e], hh, mm, ll);
          uh[e] = hh; um[e] = mm; ul[e] = ll;
        }
        const int p = gran ^ (row & 15);
        *reinterpret_cast<us8*>(&Hml[cur ^ 1][0][row][p << 3]) = uh;
        *reinterpret_cast<us8*>(&Hml[cur ^ 1][1][row][p << 3]) = um;
        *reinterpret_cast<us8*>(&Hml[cur ^ 1][2][row][p << 3]) = ul;
      }
    }
    __syncthreads();
  }

  // ---- K-split pair reduce: odd wave -> LDS, even wave adds ----
  if (w & 1) {
    float* dst = PG + (rw << 10);
    #pragma unroll
    for (int ti = 0; ti < 2; ++ti)
      #pragma unroll
      for (int tj = 0; tj < 2; ++tj)
        *reinterpret_cast<f32x4*>(dst + (((ti << 1) + tj) << 8) + (l << 2)) = acc[ti][tj];
  }
  __syncthreads();
  if (!(w & 1)) {
    const float* src = PG + (rw << 10);
    #pragma unroll
    for (int ti = 0; ti < 2; ++ti)
      #pragma unroll
      for (int tj = 0; tj < 2; ++tj)
        acc[ti][tj] += *reinterpret_cast<const f32x4*>(src + (((ti << 1) + tj) << 8) + (l << 2));
  }
  __syncthreads();
  // even waves scatter G into PG[64][PGS] (C/D layout: col=l&15, row=4*(l>>4)+reg)
  if (!(w & 1)) {
    #pragma unroll
    for (int ti = 0; ti < 2; ++ti)
      #pragma unroll
      for (int tj = 0; tj < 2; ++tj)
        #pragma unroll
        for (int reg = 0; reg < 4; ++reg) {
          const int grow = (R << 5) + (ti << 4) + ((l >> 4) << 2) + reg;
          const int gcol = (C << 5) + (tj << 4) + (l & 15);
          PG[grow * PGS + gcol] = acc[ti][tj][reg];
        }
  }
  __syncthreads();

  // ---- distances in place ----
  if (t < NPTS) diagf[t] = PG[t * PGS + t];
  __syncthreads();
  {
    const int r  = t >> 3;
    const int c0 = (t & 7) << 3;
    const float dr = diagf[r];
    #pragma unroll
    for (int e = 0; e < 8; ++e) {
      const int cc = c0 + e;
      const float gg = PG[r * PGS + cc];
      float d2 = dr + diagf[cc] - 2.f * gg;
      d2 = fmaxf(d2, 0.f);
      PG[r * PGS + cc] = (d2 > 0.f) ? sqrtf(d2) : 0.f;
    }
  }
  __syncthreads();
  if (w != 0) return;            // wave 0 runs the MST tail

  // ============== MST clustering (single wave, lane l = point l) ============
  // row l into registers (never modified again)
  float drow[64];
  #pragma unroll
  for (int v4 = 0; v4 < 16; ++v4) {
    f32x4 x = *reinterpret_cast<const f32x4*>(&PG[l * PGS + (v4 << 2)]);
    drow[v4 * 4 + 0] = x[0]; drow[v4 * 4 + 1] = x[1];
    drow[v4 * 4 + 2] = x[2]; drow[v4 * 4 + 3] = x[3];
  }
  int tl = labels[b * NPTS + l];

  unsigned long long sMask = 0ull;
  int kcnt = 0;
  #pragma unroll
  for (int v = 0; v < 8; ++v) {
    unsigned long long mv = __ballot(tl == v);
    kcnt += (mv != 0ull) ? 1 : 0;
    if (tl == v) sMask = mv;
  }
  int simC = __popcll(sMask);
  const int merges = NPTS - kcnt;

  float simS = 0.f, disS = 0.f;
  #pragma unroll
  for (int j = 0; j < NPTS; ++j) {
    bool sim = (sMask >> j) & 1ull;
    simS += sim ? drow[j] : 0.f;
    disS += sim ? 0.f : drow[j];
  }

  // init
  comp_s[l] = l; lab_s[l] = l;
  if (l == 0) ecnt_s = 0;
  lds_fence();

  // ---- Boruvka: 6 rounds (64 -> 1 comps guaranteed) ----
  #pragma unroll 1
  for (int rd = 0; rd < 6; ++rd) {
    bw_s[l] = 0xFFFFFFFFu; bfl_s[l] = 0xFFFFFFFFu;
    lds_fence();
    const int myc = comp_s[l];
    // masked row argmin (strict <: lowest j wins ties)
    float bv = BIGF; int bj = 64;
    #pragma unroll
    for (int jc = 0; jc < 16; ++jc) {
      int4 c4 = *reinterpret_cast<const int4*>(&comp_s[jc << 2]);
      int cj[4] = {c4.x, c4.y, c4.z, c4.w};
      #pragma unroll
      for (int e = 0; e < 4; ++e) {
        const int j = (jc << 2) + e;
        bool ok = (cj[e] != myc) && (drow[j] < bv);
        bv = ok ? drow[j] : bv;
        bj = ok ? j : bj;
      }
    }
    // per-comp min: stage 1 = weight bits (positive floats: uint order)
    if (bj < 64) atomicMin(&bw_s[myc], __float_as_uint(bv));
    lds_fence();
    unsigned bwc = bw_s[myc];
    if (bj < 64 && __float_as_uint(bv) == bwc)
      atomicMin(&bfl_s[myc], (unsigned)((l << 6) | bj));   // stage 2 = lowest flat
    lds_fence();
    // hooking
    const bool isroot = (myc == l);
    const unsigned rw_ = bw_s[l];
    const unsigned rf  = bfl_s[l];
    int hook = l;
    if (isroot && rw_ != 0xFFFFFFFFu)
      hook = comp_s[rf & 63];          // comp of other endpoint
    ptr_s[l] = isroot ? hook : myc;
    lds_fence();
    // mutual-pair fix + MST edge add (adder = non-surviving root)
    if (isroot && hook != l) {
      const int pd = ptr_s[hook];
      if (pd == l && l < hook) {
        ptr_s[l] = l;                  // smaller root survives, adds nothing
      } else {
        int slot = atomicAdd(&ecnt_s, 1);
        ekey_s[slot & 63] = ((unsigned long long)rw_ << 32) | (unsigned long long)rf;
      }
    }
    lds_fence();
    // pointer doubling (6x covers chains up to 64; stale reads are safe)
    #pragma unroll 1
    for (int jj = 0; jj < 6; ++jj) {
      int pp = ptr_s[l];
      int p2 = ptr_s[pp & 63];
      ptr_s[l] = p2;
    }
    lds_fence();
    comp_s[l] = ptr_s[l];
    lds_fence();
  }

  // ---- edge selection: keep the `merges` smallest (w, flat) keys ----
  const int ec = ecnt_s;               // 63 in all non-degenerate cases
  const bool ehave = (l < ec);
  const unsigned long long my = ehave ? ekey_s[l] : ~0ull;
  int rank = 0;
  #pragma unroll 7
  for (int j = 0; j < 63; ++j) {
    unsigned long long kj = ekey_s[j]; // broadcast read (all lanes same addr)
    rank += (j < ec && kj < my) ? 1 : 0;
  }
  const bool kept = ehave && (rank < merges);
  const int eu = (int)((my >> 6) & 63);
  const int ev = (int)(my & 63);

  // ---- label propagation on kept edges (min-index label per component) ----
  #pragma unroll 1
  for (int iter = 0; iter < 64; ++iter) {
    int m = 0; bool ch = false;
    if (kept) {
      int lu = lab_s[eu], lv = lab_s[ev];
      m = min(lu, lv);
      ch = (m < lu) || (m < lv);
    }
    if (__ballot(ch) == 0ull) break;
    if (ch) {
      atomicMin(&lab_s[eu], m);
      atomicMin(&lab_s[ev], m);
    }
    lds_fence();
  }
  lds_fence();
  const int cl = lab_s[l];

  // err count via masks
  cls[l] = cl;
  lds_fence();
  unsigned long long cMask = 0ull;
  const int4* cp = reinterpret_cast<const int4*>(cls);
  #pragma unroll 4
  for (int jq = 0; jq < 16; ++jq) {
    int4 c4 = cp[jq];
    cMask |= ((unsigned long long)(c4.x == cl)) << (jq * 4 + 0);
    cMask |= ((unsigned long long)(c4.y == cl)) << (jq * 4 + 1);
    cMask |= ((unsigned long long)(c4.z == cl)) << (jq * 4 + 2);
    cMask |= ((unsigned long long)(c4.w == cl)) << (jq * 4 + 3);
  }
  int ec2 = __popcll(cMask ^ sMask);

  #pragma unroll
  for (int off = 32; off; off >>= 1) {
    simS += __shfl_xor(simS, off);
    disS += __shfl_xor(disS, off);
    simC += __shfl_xor(simC, off);
    ec2  += __shfl_xor(ec2, off);
  }
  if (l == 0) {
    simS_o[b] = simS; disS_o[b] = disS;
    simC_o[b] = simC; errC_o[b] = ec2;
  }
}

__global__ __launch_bounds__(64) void finalize_kernel(
    const float* __restrict__ simS, const float* __restrict__ disS,
    const int* __restrict__ simC, const int* __restrict__ errC,
    float* __restrict__ out)
{
  const int l = threadIdx.x;
  double ss = 0.0, dd = 0.0, sc = 0.0, ec = 0.0;
  #pragma unroll
  for (int r = 0; r < 4; ++r) {
    int i = (r << 6) + l;
    ss += (double)simS[i];
    dd += (double)disS[i];
    sc += (double)simC[i];
    ec += (double)errC[i];
  }
  #pragma unroll
  for (int off = 32; off; off >>= 1) {
    ss += __shfl_xor(ss, off);
    dd += __shfl_xor(dd, off);
    sc += __shfl_xor(sc, off);
    ec += __shfl_xor(ec, off);
  }
  if (l == 0) {
    const double total = 256.0 * 4096.0;
    double ms = ss / sc;
    double md = dd / (total - sc);
    out[0] = (float)(ec / 256.0 + 0.5 * (ms - md));
  }
}

extern "C" void kernel_launch(void* const* d_in, const int* in_sizes, int n_in,
                              void* d_out, int out_size, void* d_ws, size_t ws_size,
                              hipStream_t stream) {
  const float* q      = (const float*)d_in[0];
  const float* psg    = (const float*)d_in[1];
  const int*   labels = (const int*)d_in[2];
  float* out = (float*)d_out;

  float* simS = (float*)d_ws;          // [256]
  float* disS = simS + 256;            // [256]
  int*   simC = (int*)(disS + 256);    // [256]
  int*   errC = simC + 256;            // [256]

  fused_kernel<<<256, NT, 0, stream>>>(q, psg, labels, simS, disS, simC, errC);
  finalize_kernel<<<1, 64, 0, stream>>>(simS, disS, simC, errC, out);
}

// Round 11
// 32.411 us; speedup vs baseline: 3.0951x; 1.1272x over previous
//
#include <hip/hip_runtime.h>

// QuerySpecificClusterModel: B=256 samples, n=64 points, d=768.
// Round 11: (1) depth-2 psg prefetch in the Gram c-loop (2-half unrolled, two
// NAMED register sets pvaA/pvaB -> static indexing, rule #20; chunk loads now
// issued a full iteration before their stage consumes them, hiding the ~1us
// per-chunk HBM transfer that depth-1 exposed). MFMA order unchanged -> Gram
// bit-identical. (2) MST tail: ballot-exit pointer doubling + early round
// exit once a single component remains. Cluster results identical.

#define NPTS 64
#define DIM 768
#define CH 128
#define NCH 6
#define NT 512
#define BIGF 1e9f
#define PGS 68

typedef __attribute__((ext_vector_type(8))) __bf16 bf16x8;
typedef __attribute__((ext_vector_type(4))) float f32x4;
typedef __attribute__((ext_vector_type(8))) unsigned short us8;

// cross-lane LDS visibility fence within one wave (guide rule #18)
__device__ __forceinline__ void lds_fence() {
  asm volatile("s_waitcnt lgkmcnt(0)" ::: "memory");
  __builtin_amdgcn_sched_barrier(0);
}

// ---- exact 3-way bf16 split: x == h + m + l ----
__device__ __forceinline__ void split3(float x, unsigned short& h,
                                       unsigned short& m, unsigned short& l) {
  unsigned u = __float_as_uint(x);
  unsigned rb = (u + 0x7FFFu + ((u >> 16) & 1u)) & 0xFFFF0000u;   // RNE
  h = (unsigned short)(rb >> 16);
  float r1 = x - __uint_as_float(rb);                              // exact
  unsigned u1 = __float_as_uint(r1);
  unsigned rb1 = (u1 + 0x7FFFu + ((u1 >> 16) & 1u)) & 0xFFFF0000u;
  m = (unsigned short)(rb1 >> 16);
  float r2 = r1 - __uint_as_float(rb1);                            // exact
  l = (unsigned short)(__float_as_uint(r2) >> 16);                 // exact
}

// stage one chunk (scale by q, split3, swizzled LDS write). Hb = Hml[buf].
__device__ __forceinline__ void stage_chunk(
    unsigned short (*Hb)[NPTS][CH], const float4 (&pva)[2][2],
    const float4 (&qv)[2], int row0, int gran) {
  #pragma unroll
  for (int rr = 0; rr < 2; ++rr) {
    const int row = row0 + (rr << 5);
    float xs[8];
    xs[0] = pva[rr][0].x * qv[0].x; xs[1] = pva[rr][0].y * qv[0].y;
    xs[2] = pva[rr][0].z * qv[0].z; xs[3] = pva[rr][0].w * qv[0].w;
    xs[4] = pva[rr][1].x * qv[1].x; xs[5] = pva[rr][1].y * qv[1].y;
    xs[6] = pva[rr][1].z * qv[1].z; xs[7] = pva[rr][1].w * qv[1].w;
    us8 uh, um, ul;
    #pragma unroll
    for (int e = 0; e < 8; ++e) {
      unsigned short hh, mm, ll;
      split3(xs[e], hh, mm, ll);
      uh[e] = hh; um[e] = mm; ul[e] = ll;
    }
    const int p = gran ^ (row & 15);
    *reinterpret_cast<us8*>(&Hb[0][row][p << 3]) = uh;
    *reinterpret_cast<us8*>(&Hb[1][row][p << 3]) = um;
    *reinterpret_cast<us8*>(&Hb[2][row][p << 3]) = ul;
  }
}

// one chunk of MFMA work for this wave. Hb = Hml[buf].
__device__ __forceinline__ void mfma_chunk(
    const unsigned short (*Hb)[NPTS][CH], f32x4 (&acc)[2][2],
    int R, int C, int ksub, int lrow, int lhi) {
  #pragma unroll 1
  for (int ss = 0; ss < 2; ++ss) {
    const int s = ksub + (ss << 1);
    const int p = ((s << 2) + lhi) ^ lrow;
    bf16x8 fa[3][2], fb[3][2];
    #pragma unroll
    for (int v = 0; v < 3; ++v)
      #pragma unroll
      for (int tb = 0; tb < 2; ++tb) {
        const int row = (R << 5) + (tb << 4) + lrow;
        fa[v][tb] = *reinterpret_cast<const bf16x8*>(&Hb[v][row][p << 3]);
      }
    if (R != C) {
      #pragma unroll
      for (int v = 0; v < 3; ++v)
        #pragma unroll
        for (int tb = 0; tb < 2; ++tb) {
          const int row = (C << 5) + (tb << 4) + lrow;
          fb[v][tb] = *reinterpret_cast<const bf16x8*>(&Hb[v][row][p << 3]);
        }
    } else {
      #pragma unroll
      for (int v = 0; v < 3; ++v)
        #pragma unroll
        for (int tb = 0; tb < 2; ++tb) fb[v][tb] = fa[v][tb];
    }
    #pragma unroll
    for (int ti = 0; ti < 2; ++ti)
      #pragma unroll
      for (int tj = 0; tj < 2; ++tj) {
        acc[ti][tj] = __builtin_amdgcn_mfma_f32_16x16x32_bf16(fa[0][ti], fb[0][tj], acc[ti][tj], 0, 0, 0); // hh
        acc[ti][tj] = __builtin_amdgcn_mfma_f32_16x16x32_bf16(fa[0][ti], fb[1][tj], acc[ti][tj], 0, 0, 0); // hm
        acc[ti][tj] = __builtin_amdgcn_mfma_f32_16x16x32_bf16(fa[1][ti], fb[0][tj], acc[ti][tj], 0, 0, 0); // mh
        acc[ti][tj] = __builtin_amdgcn_mfma_f32_16x16x32_bf16(fa[1][ti], fb[1][tj], acc[ti][tj], 0, 0, 0); // mm
        acc[ti][tj] = __builtin_amdgcn_mfma_f32_16x16x32_bf16(fa[0][ti], fb[2][tj], acc[ti][tj], 0, 0, 0); // hl
        acc[ti][tj] = __builtin_amdgcn_mfma_f32_16x16x32_bf16(fa[2][ti], fb[0][tj], acc[ti][tj], 0, 0, 0); // lh
      }
  }
}

#define ISSUE_P(PV, cix) do {                                       \
    const int off_ = (cix) * CH;                                    \
    PV[0][0] = *(const float4*)(pr0 + off_);                        \
    PV[0][1] = *(const float4*)(pr0 + off_ + 4);                    \
    PV[1][0] = *(const float4*)(pr1 + off_);                        \
    PV[1][1] = *(const float4*)(pr1 + off_ + 4);                    \
  } while (0)

#define ISSUE_Q(QV, cix) do {                                       \
    const int off_ = (cix) * CH;                                    \
    QV[0] = *(const float4*)(qr + off_);                            \
    QV[1] = *(const float4*)(qr + off_ + 4);                        \
  } while (0)

// ============ fused kernel: MFMA Gram -> distances -> MST clustering ========
__global__ __launch_bounds__(NT) void fused_kernel(
    const float* __restrict__ q,      // [256,768]
    const float* __restrict__ psg,    // [256,64,768]
    const int*   __restrict__ labels, // [256,64]
    float* __restrict__ simS_o, float* __restrict__ disS_o,
    int* __restrict__ simC_o, int* __restrict__ errC_o)
{
  __shared__ __align__(16) unsigned short Hml[2][3][NPTS][CH]; // 96 KB dbuf
  __shared__ __align__(16) float PG[NPTS * PGS];
  __shared__ float diagf[NPTS];
  __shared__ __align__(16) int cls[NPTS];
  __shared__ __align__(16) int comp_s[NPTS];
  __shared__ unsigned bw_s[NPTS], bfl_s[NPTS];
  __shared__ int ptr_s[NPTS], lab_s[NPTS];
  __shared__ __align__(8) unsigned long long ekey_s[NPTS];
  __shared__ int ecnt_s;

  const int b = blockIdx.x;
  const int t = threadIdx.x;
  const int w = t >> 6;
  const int l = t & 63;

  const float* qb = q + (size_t)b * DIM;
  const float* pb = psg + (size_t)b * NPTS * DIM;

  const int row0 = t >> 4;
  const int gran = t & 15;
  const float* pr0 = pb + (size_t)row0 * DIM + (gran << 3);
  const float* pr1 = pr0 + 32 * DIM;
  const float* qr  = qb + (gran << 3);

  const int rw = w >> 1;
  const int R = rw >> 1, C = rw & 1;
  const int ksub = w & 1;
  const int lrow = l & 15;
  const int lhi  = l >> 4;

  f32x4 acc[2][2];
  {
    f32x4 z = {0.f, 0.f, 0.f, 0.f};
    acc[0][0] = z; acc[0][1] = z; acc[1][0] = z; acc[1][1] = z;
  }

  // two NAMED prefetch sets (static indexing; rule #20)
  float4 pvaA[2][2], pvaB[2][2], qv[2];

  // prologue: chunk0 -> A, chunk1 -> B; stage chunk0
  ISSUE_P(pvaA, 0);
  ISSUE_Q(qv, 0);
  ISSUE_P(pvaB, 1);
  stage_chunk(Hml[0], pvaA, qv, row0, gran);
  __syncthreads();

  // main loop: 2 chunks per iteration, depth-2 prefetch
  #pragma unroll 1
  for (int cc = 0; cc < 3; ++cc) {
    // ---- half A: compute chunk 2cc (buf0), stage 2cc+1 (from B -> buf1) ----
    if (cc < 2) ISSUE_P(pvaA, 2 * cc + 2);      // refill A two chunks ahead
    ISSUE_Q(qv, 2 * cc + 1);                    // q for the chunk staged below
    mfma_chunk(Hml[0], acc, R, C, ksub, lrow, lhi);
    stage_chunk(Hml[1], pvaB, qv, row0, gran);
    __syncthreads();
    // ---- half B: compute chunk 2cc+1 (buf1), stage 2cc+2 (from A -> buf0) --
    if (cc < 2) {
      ISSUE_P(pvaB, 2 * cc + 3);
      ISSUE_Q(qv, 2 * cc + 2);
    }
    mfma_chunk(Hml[1], acc, R, C, ksub, lrow, lhi);
    if (cc < 2) stage_chunk(Hml[0], pvaA, qv, row0, gran);
    __syncthreads();
  }

  // ---- K-split pair reduce: odd wave -> LDS, even wave adds ----
  if (w & 1) {
    float* dst = PG + (rw << 10);
    #pragma unroll
    for (int ti = 0; ti < 2; ++ti)
      #pragma unroll
      for (int tj = 0; tj < 2; ++tj)
        *reinterpret_cast<f32x4*>(dst + (((ti << 1) + tj) << 8) + (l << 2)) = acc[ti][tj];
  }
  __syncthreads();
  if (!(w & 1)) {
    const float* src = PG + (rw << 10);
    #pragma unroll
    for (int ti = 0; ti < 2; ++ti)
      #pragma unroll
      for (int tj = 0; tj < 2; ++tj)
        acc[ti][tj] += *reinterpret_cast<const f32x4*>(src + (((ti << 1) + tj) << 8) + (l << 2));
  }
  __syncthreads();
  if (!(w & 1)) {
    #pragma unroll
    for (int ti = 0; ti < 2; ++ti)
      #pragma unroll
      for (int tj = 0; tj < 2; ++tj)
        #pragma unroll
        for (int reg = 0; reg < 4; ++reg) {
          const int grow = (R << 5) + (ti << 4) + (lhi << 2) + reg;
          const int gcol = (C << 5) + (tj << 4) + lrow;
          PG[grow * PGS + gcol] = acc[ti][tj][reg];
        }
  }
  __syncthreads();

  // ---- distances in place ----
  if (t < NPTS) diagf[t] = PG[t * PGS + t];
  __syncthreads();
  {
    const int r  = t >> 3;
    const int c0 = (t & 7) << 3;
    const float dr = diagf[r];
    #pragma unroll
    for (int e = 0; e < 8; ++e) {
      const int cc = c0 + e;
      const float gg = PG[r * PGS + cc];
      float d2 = dr + diagf[cc] - 2.f * gg;
      d2 = fmaxf(d2, 0.f);
      PG[r * PGS + cc] = (d2 > 0.f) ? sqrtf(d2) : 0.f;
    }
  }
  __syncthreads();
  if (w != 0) return;            // wave 0 runs the MST tail

  // ============== MST clustering (single wave, lane l = point l) ============
  float drow[64];
  #pragma unroll
  for (int v4 = 0; v4 < 16; ++v4) {
    f32x4 x = *reinterpret_cast<const f32x4*>(&PG[l * PGS + (v4 << 2)]);
    drow[v4 * 4 + 0] = x[0]; drow[v4 * 4 + 1] = x[1];
    drow[v4 * 4 + 2] = x[2]; drow[v4 * 4 + 3] = x[3];
  }
  int tl = labels[b * NPTS + l];

  unsigned long long sMask = 0ull;
  int kcnt = 0;
  #pragma unroll
  for (int v = 0; v < 8; ++v) {
    unsigned long long mv = __ballot(tl == v);
    kcnt += (mv != 0ull) ? 1 : 0;
    if (tl == v) sMask = mv;
  }
  int simC = __popcll(sMask);
  const int merges = NPTS - kcnt;

  float simS = 0.f, disS = 0.f;
  #pragma unroll
  for (int j = 0; j < NPTS; ++j) {
    bool sim = (sMask >> j) & 1ull;
    simS += sim ? drow[j] : 0.f;
    disS += sim ? 0.f : drow[j];
  }

  comp_s[l] = l; lab_s[l] = l;
  if (l == 0) ecnt_s = 0;
  lds_fence();

  // ---- Boruvka with early exits ----
  #pragma unroll 1
  for (int rd = 0; rd < 6; ++rd) {
    bw_s[l] = 0xFFFFFFFFu; bfl_s[l] = 0xFFFFFFFFu;
    lds_fence();
    const int myc = comp_s[l];
    float bv = BIGF; int bj = 64;
    #pragma unroll
    for (int jc = 0; jc < 16; ++jc) {
      int4 c4 = *reinterpret_cast<const int4*>(&comp_s[jc << 2]);
      int cj[4] = {c4.x, c4.y, c4.z, c4.w};
      #pragma unroll
      for (int e = 0; e < 4; ++e) {
        const int j = (jc << 2) + e;
        bool ok = (cj[e] != myc) && (drow[j] < bv);
        bv = ok ? drow[j] : bv;
        bj = ok ? j : bj;
      }
    }
    if (bj < 64) atomicMin(&bw_s[myc], __float_as_uint(bv));
    lds_fence();
    unsigned bwc = bw_s[myc];
    if (bj < 64 && __float_as_uint(bv) == bwc)
      atomicMin(&bfl_s[myc], (unsigned)((l << 6) | bj));
    lds_fence();
    const bool isroot = (myc == l);
    const unsigned rw_ = bw_s[l];
    const unsigned rf  = bfl_s[l];
    int hook = l;
    if (isroot && rw_ != 0xFFFFFFFFu)
      hook = comp_s[rf & 63];
    ptr_s[l] = isroot ? hook : myc;
    lds_fence();
    if (isroot && hook != l) {
      const int pd = ptr_s[hook];
      if (pd == l && l < hook) {
        ptr_s[l] = l;
      } else {
        int slot = atomicAdd(&ecnt_s, 1);
        ekey_s[slot & 63] = ((unsigned long long)rw_ << 32) | (unsigned long long)rf;
      }
    }
    lds_fence();
    // pointer doubling, ballot-exit (converges in ~2-3 iters)
    #pragma unroll 1
    for (int jj = 0; jj < 6; ++jj) {
      int pp = ptr_s[l];
      int p2 = ptr_s[pp & 63];
      if (__ballot(p2 != pp) == 0ull) break;
      ptr_s[l] = p2;
    }
    lds_fence();
    const int newc = ptr_s[l];
    comp_s[l] = newc;
    lds_fence();
    // early exit once a single component remains
    const int base = __shfl(newc, 0);
    if (__ballot(newc != base) == 0ull) break;
  }

  // ---- edge selection: keep the `merges` smallest (w, flat) keys ----
  const int ec = ecnt_s;
  const bool ehave = (l < ec);
  const unsigned long long my = ehave ? ekey_s[l] : ~0ull;
  int rank = 0;
  #pragma unroll 7
  for (int j = 0; j < 63; ++j) {
    unsigned long long kj = ekey_s[j];
    rank += (j < ec && kj < my) ? 1 : 0;
  }
  const bool kept = ehave && (rank < merges);
  const int eu = (int)((my >> 6) & 63);
  const int ev = (int)(my & 63);

  // ---- label propagation on kept edges ----
  #pragma unroll 1
  for (int iter = 0; iter < 64; ++iter) {
    int m = 0; bool ch = false;
    if (kept) {
      int lu = lab_s[eu], lv = lab_s[ev];
      m = min(lu, lv);
      ch = (m < lu) || (m < lv);
    }
    if (__ballot(ch) == 0ull) break;
    if (ch) {
      atomicMin(&lab_s[eu], m);
      atomicMin(&lab_s[ev], m);
    }
    lds_fence();
  }
  lds_fence();
  const int cl = lab_s[l];

  cls[l] = cl;
  lds_fence();
  unsigned long long cMask = 0ull;
  const int4* cp = reinterpret_cast<const int4*>(cls);
  #pragma unroll 4
  for (int jq = 0; jq < 16; ++jq) {
    int4 c4 = cp[jq];
    cMask |= ((unsigned long long)(c4.x == cl)) << (jq * 4 + 0);
    cMask |= ((unsigned long long)(c4.y == cl)) << (jq * 4 + 1);
    cMask |= ((unsigned long long)(c4.z == cl)) << (jq * 4 + 2);
    cMask |= ((unsigned long long)(c4.w == cl)) << (jq * 4 + 3);
  }
  int ec2 = __popcll(cMask ^ sMask);

  #pragma unroll
  for (int off = 32; off; off >>= 1) {
    simS += __shfl_xor(simS, off);
    disS += __shfl_xor(disS, off);
    simC += __shfl_xor(simC, off);
    ec2  += __shfl_xor(ec2, off);
  }
  if (l == 0) {
    simS_o[b] = simS; disS_o[b] = disS;
    simC_o[b] = simC; errC_o[b] = ec2;
  }
}

__global__ __launch_bounds__(64) void finalize_kernel(
    const float* __restrict__ simS, const float* __restrict__ disS,
    const int* __restrict__ simC, const int* __restrict__ errC,
    float* __restrict__ out)
{
  const int l = threadIdx.x;
  double ss = 0.0, dd = 0.0, sc = 0.0, ec = 0.0;
  #pragma unroll
  for (int r = 0; r < 4; ++r) {
    int i = (r << 6) + l;
    ss += (double)simS[i];
    dd += (double)disS[i];
    sc += (double)simC[i];
    ec += (double)errC[i];
  }
  #pragma unroll
  for (int off = 32; off; off >>= 1) {
    ss += __shfl_xor(ss, off);
    dd += __shfl_xor(dd, off);
    sc += __shfl_xor(sc, off);
    ec += __shfl_xor(ec, off);
  }
  if (l == 0) {
    const double total = 256.0 * 4096.0;
    double ms = ss / sc;
    double md = dd / (total - sc);
    out[0] = (float)(ec / 256.0 + 0.5 * (ms - md));
  }
}

extern "C" void kernel_launch(void* const* d_in, const int* in_sizes, int n_in,
                              void* d_out, int out_size, void* d_ws, size_t ws_size,
                              hipStream_t stream) {
  const float* q      = (const float*)d_in[0];
  const float* psg    = (const float*)d_in[1];
  const int*   labels = (const int*)d_in[2];
  float* out = (float*)d_out;

  float* simS = (float*)d_ws;          // [256]
  float* disS = simS + 256;            // [256]
  int*   simC = (int*)(disS + 256);    // [256]
  int*   errC = simC + 256;            // [256]

  fused_kernel<<<256, NT, 0, stream>>>(q, psg, labels, simS, disS, simC, errC);
  finalize_kernel<<<1, 64, 0, stream>>>(simS, disS, simC, errC, out);
}